// Round 7
// baseline (234.246 us; speedup 1.0000x reference)
//
#include <hip/hip_runtime.h>

namespace {
constexpr int SD = 1024;           // D
constexpr int TD = 2048;           // 2D
constexpr int BATCH = 8;
constexpr int IDIM = 64;
constexpr int RH = 4;
constexpr float EPSc = 1e-5f;
constexpr float DXf = 2.0f / 31.0f;
constexpr float DXDYf = DXf * DXf;
constexpr float SCALEf = 0.125f;
constexpr float CFINAL = DXDYf * DXDYf * SCALEf;

// workspace offsets (in floats); all multiples of 4 -> float4 safe
constexpr size_t OFF_V   = 0;
constexpr size_t OFF_MID = OFF_V   + (size_t)BATCH * TD * IDIM;   // 1048576
constexpr size_t OFF_W   = OFF_MID + (size_t)BATCH * TD * IDIM;
constexpr size_t OFF_WF  = OFF_W   + (size_t)SD * SD;
constexpr size_t OFF_U1K = OFF_WF  + (size_t)SD * SD;
constexpr size_t OFF_U2K = OFF_U1K + SD * 32;
constexpr size_t OFF_U1F = OFF_U2K + SD * 32;
constexpr size_t OFF_U2F = OFF_U1F + SD * 32;
constexpr size_t OFF_GP  = OFF_U2F + SD * 32;                      // 8*32*4096
constexpr size_t OFF_SP  = OFF_GP  + (size_t)BATCH * 32 * 4096;    // 8*32*64
constexpr size_t OFF_A   = OFF_SP  + BATCH * 32 * 64;              // (dead)
constexpr size_t OFF_RV  = OFF_A   + BATCH * 4096;                 // (dead)
constexpr size_t OFF_LNP = OFF_RV  + BATCH * 64;                   // 8*32*2
constexpr size_t OFF_ZU  = OFF_LNP + BATCH * 32 * 2;               // (f32 Z dead this round -> P3)
constexpr size_t OFF_ZF  = OFF_ZU  + (size_t)SD * 512;
constexpr size_t OFF_W1  = OFF_ZF  + (size_t)SD * 512;
constexpr size_t OFF_CS  = OFF_W1  + SD;                           // 16*1024 colsum partials
constexpr size_t WS_FLOATS = OFF_CS + 16 * SD;
// tail overlays (no growth):
//   G->U1K(+U2K), SV->U1F, PM->GP+524288, RP->SP
//   Wbf  (1024x1024 bf16) -> OFF_W   (512K floats of the 1M region)
//   Wfbf (1024x1024 bf16) -> OFF_WF
//   WbfT (1024x2048 bf16 = 1,048,576 fl) -> V   [V dead after k_y]
//   ZT   (512x2048 bf16  =   524,288 fl) -> MID [MID dead after j-loop]
//   P0->GP, P1->GP+524288, P2->MID+524288, P3->ZU
} // namespace

typedef __bf16 bf16x8 __attribute__((ext_vector_type(8)));
typedef float f32x4 __attribute__((ext_vector_type(4)));

__device__ __forceinline__ float leaky(float x) { return fmaxf(x, 0.01f * x); }
__device__ __forceinline__ float gxv(int i) { return -1.0f + (2.0f / 31.0f) * (float)i; }
__device__ __forceinline__ ushort f2bf(float x) { union { __bf16 b; ushort u; } v; v.b = (__bf16)x; return v.u; }
__device__ __forceinline__ float bf2f(ushort u) { return __uint_as_float(((uint)u) << 16); }

// ---- edge-MLP layer-1 factorization tables ----
__global__ void k_pre_u(const float* __restrict__ kW1, const float* __restrict__ kb1,
                        const float* __restrict__ fW1, const float* __restrict__ fb1,
                        float* __restrict__ u1k, float* __restrict__ u2k,
                        float* __restrict__ u1f, float* __restrict__ u2f) {
  int n = blockIdx.x * blockDim.x + threadIdx.x;
  if (n >= SD) return;
  float ga = gxv(n >> 5), gb = gxv(n & 31);
  for (int j = 0; j < 32; j++) {
    u1k[n * 32 + j] = ga * kW1[j] + gb * kW1[32 + j] + kb1[j];
    u2k[n * 32 + j] = gb * kW1[64 + j] + ga * kW1[96 + j];
    u1f[n * 32 + j] = ga * fW1[j] + gb * fW1[32 + j] + fb1[j];
    u2f[n * 32 + j] = gb * fW1[64 + j] + ga * fW1[96 + j];
  }
}

// ---- MFMA edge-MLP (swapped operands): D[o][m]; in-lane W3 dot; 2-shfl reduce; bf16 out ----
__global__ __launch_bounds__(256) void k_mlp2(
    const float* __restrict__ u1k, const float* __restrict__ u2k,
    const float* __restrict__ kW2, const float* __restrict__ kb2,
    const float* __restrict__ kW3, const float* __restrict__ kb3,
    const float* __restrict__ u1f, const float* __restrict__ u2f,
    const float* __restrict__ fW2, const float* __restrict__ fb2,
    const float* __restrict__ fW3, const float* __restrict__ fb3,
    ushort* __restrict__ outK, ushort* __restrict__ outF) {
  const int which = blockIdx.y;
  const float* u1 = which ? u1f : u1k;
  const float* u2 = which ? u2f : u2k;
  const float* W2 = which ? fW2 : kW2;
  const float* b2 = which ? fb2 : kb2;
  const float* W3 = which ? fW3 : kW3;
  const float* b3 = which ? fb3 : kb3;
  ushort* out = which ? outF : outK;

  const int t = threadIdx.x;
  const int lane = t & 63, wave = t >> 6;
  const int row = lane & 15, grp = lane >> 4;
  const int n = blockIdx.x;

  // A-operand = W2^T: wfrag[tt][i] = bf16(W2[k=grp*8+i][o=tt*16+row])
  bf16x8 wfrag[4];
  float4 b2q[4], w3q[4];   // per-reg values: index o = tt*16 + grp*4 + r
#pragma unroll
  for (int tt = 0; tt < 4; tt++) {
#pragma unroll
    for (int i = 0; i < 8; i++) wfrag[tt][i] = (__bf16)W2[(grp * 8 + i) * 64 + tt * 16 + row];
    b2q[tt] = *reinterpret_cast<const float4*>(b2 + tt * 16 + grp * 4);
    w3q[tt] = *reinterpret_cast<const float4*>(W3 + tt * 16 + grp * 4);
  }
  float u1j[8];
#pragma unroll
  for (int i = 0; i < 8; i++) u1j[i] = u1[n * 32 + grp * 8 + i];
  const float b3v = b3[0];

  for (int chunk = 0; chunk < 4; chunk++) {
#pragma unroll
    for (int st = 0; st < 4; st++) {
      int mbase = chunk * 256 + wave * 64 + st * 16;
      int m = mbase + row;
      const float4* u2p = reinterpret_cast<const float4*>(u2 + (size_t)m * 32 + grp * 8);
      float4 ua = u2p[0], ub = u2p[1];
      float hv[8] = {ua.x, ua.y, ua.z, ua.w, ub.x, ub.y, ub.z, ub.w};
      bf16x8 pfrag;   // B-operand: col=m (lane&15), k=grp*8+i
#pragma unroll
      for (int i = 0; i < 8; i++) pfrag[i] = (__bf16)leaky(u1j[i] + hv[i]);
      float accv = 0.f;
#pragma unroll
      for (int tt = 0; tt < 4; tt++) {
        f32x4 ci = {b2q[tt].x, b2q[tt].y, b2q[tt].z, b2q[tt].w};
        f32x4 c = __builtin_amdgcn_mfma_f32_16x16x32_bf16(wfrag[tt], pfrag, ci, 0, 0, 0);
        accv += leaky(c[0]) * w3q[tt].x;
        accv += leaky(c[1]) * w3q[tt].y;
        accv += leaky(c[2]) * w3q[tt].z;
        accv += leaky(c[3]) * w3q[tt].w;
      }
      // sum over the 4 grp groups (o-quarters): lanes l, l+16, l+32, l+48
      accv += __shfl_xor(accv, 16, 64);
      accv += __shfl_xor(accv, 32, 64);
      if (grp == 0) out[(size_t)n * SD + mbase + row] = f2bf(accv + b3v);
    }
  }
}

// ---- colsum stage 1 (bf16 sources): cs[r][c] = sum over 64 rows of (W+Wf) ----
__global__ __launch_bounds__(256) void k_colsum_p1(const ushort* __restrict__ W, const ushort* __restrict__ Wf,
                                                   float* __restrict__ cs) {
  int c = blockIdx.x * 256 + threadIdx.x;
  int n0 = blockIdx.y * 64;
  float s = 0.f;
  for (int r = 0; r < 64; r++)
    s += bf2f(W[(size_t)(n0 + r) * SD + c]) + bf2f(Wf[(size_t)(n0 + r) * SD + c]);
  cs[blockIdx.y * SD + c] = s;
}

__global__ __launch_bounds__(256) void k_colsum_p2(const float* __restrict__ cs, float* __restrict__ w1) {
  int c = blockIdx.x * 256 + threadIdx.x;
  float s = 0.f;
#pragma unroll
  for (int r = 0; r < 16; r++) s += cs[r * SD + c];
  w1[c] = s;
}

// ---- LN partial sums (per batch, 32 chunks of 4096) ----
__global__ __launch_bounds__(256) void k_redsum(const float* __restrict__ X, float* __restrict__ part) {
  int b = blockIdx.y, c = blockIdx.x, t = threadIdx.x;
  const float4* X4 = reinterpret_cast<const float4*>(X + (size_t)b * 131072 + (size_t)c * 4096);
  float s = 0.f, q = 0.f;
#pragma unroll
  for (int k = 0; k < 4; k++) {
    float4 v = X4[t + k * 256];
    s += v.x + v.y + v.z + v.w;
    q += v.x * v.x + v.y * v.y + v.z * v.z + v.w * v.w;
  }
  for (int off = 32; off; off >>= 1) { s += __shfl_down(s, off); q += __shfl_down(q, off); }
  __shared__ float ss[4], qq[4];
  int lane = t & 63, wid = t >> 6;
  if (lane == 0) { ss[wid] = s; qq[wid] = q; }
  __syncthreads();
  if (t == 0) {
    part[(size_t)(b * 32 + c) * 2] = ss[0] + ss[1] + ss[2] + ss[3];
    part[(size_t)(b * 32 + c) * 2 + 1] = qq[0] + qq[1] + qq[2] + qq[3];
  }
}

// ---- apply LN (stats inline from 32 partials): dst = (src-mean)*invstd*g + b (+ addv) ----
__global__ __launch_bounds__(256) void k_apply(const float* __restrict__ src, const float* __restrict__ g,
                                               const float* __restrict__ bb, const float* __restrict__ lnp,
                                               const float* __restrict__ addv, float* __restrict__ dst) {
  __shared__ float sm[2];
  int i4 = blockIdx.x * 256 + threadIdx.x;  // 0..262143
  int b = i4 >> 15;                          // uniform within block
  if (threadIdx.x == 0) {
    float s = 0.f, q = 0.f;
    for (int c = 0; c < 32; c++) { s += lnp[(size_t)(b * 32 + c) * 2]; q += lnp[(size_t)(b * 32 + c) * 2 + 1]; }
    float mean = s / 131072.0f;
    sm[0] = mean;
    sm[1] = rsqrtf(q / 131072.0f - mean * mean + EPSc);
  }
  __syncthreads();
  float mean = sm[0], is = sm[1];
  int p4 = i4 & 32767;
  float4 v = reinterpret_cast<const float4*>(src)[i4];
  float4 gg = reinterpret_cast<const float4*>(g)[p4];
  float4 bv = reinterpret_cast<const float4*>(bb)[p4];
  float4 r;
  r.x = (v.x - mean) * is * gg.x + bv.x;
  r.y = (v.y - mean) * is * gg.y + bv.y;
  r.z = (v.z - mean) * is * gg.z + bv.z;
  r.w = (v.w - mean) * is * gg.w + bv.w;
  if (addv != nullptr) {
    float4 av = reinterpret_cast<const float4*>(addv)[i4];
    r.x += av.x; r.y += av.y; r.z += av.z; r.w += av.w;
  }
  reinterpret_cast<float4*>(dst)[i4] = r;
}

// ---- chunked X^T Y (64 rows/chunk), q-split over blockIdx.z; + colsum(Y) partials ----
__global__ __launch_bounds__(256) void k_xty(const float* __restrict__ Xb, const float* __restrict__ Yb,
                                             float* __restrict__ Gp, float* __restrict__ sp) {
  int c = blockIdx.x, b = blockIdx.y, zh = blockIdx.z, t = threadIdx.x;
  int nch = gridDim.x;
  const float4* X4 = reinterpret_cast<const float4*>(Xb + (size_t)b * 131072 + (size_t)c * 4096);
  const float4* Y4 = reinterpret_cast<const float4*>(Yb + (size_t)b * 131072 + (size_t)c * 4096);
  __shared__ __align__(16) float Xs[4096];
  __shared__ __align__(16) float Ys[4096];
#pragma unroll
  for (int k = 0; k < 4; k++) {
    reinterpret_cast<float4*>(Xs)[t + k * 256] = X4[t + k * 256];
    reinterpret_cast<float4*>(Ys)[t + k * 256] = Y4[t + k * 256];
  }
  __syncthreads();
  int p = t >> 2, ql = zh * 32 + (t & 3) * 8;
  float4 acc[2] = {};
  for (int k = 0; k < 64; k++) {
    float xv = Xs[k * 64 + p];
    const float4* y = reinterpret_cast<const float4*>(&Ys[k * 64 + ql]);
#pragma unroll
    for (int u = 0; u < 2; u++) {
      float4 yv = y[u];
      acc[u].x += xv * yv.x; acc[u].y += xv * yv.y; acc[u].z += xv * yv.z; acc[u].w += xv * yv.w;
    }
  }
  float* go = Gp + (size_t)(b * nch + c) * 4096 + p * 64 + ql;
#pragma unroll
  for (int u = 0; u < 2; u++) reinterpret_cast<float4*>(go)[u] = acc[u];
  if (zh == 0 && t < 64) {
    float ssum = 0.f;
    for (int k = 0; k < 64; k++) ssum += Ys[k * 64 + t];
    sp[(size_t)(b * nch + c) * 64 + t] = ssum;
  }
}

// ---- coalesced partial reduction: G = sum_c Gp[c], sv = sum_c sp[c] ----
__global__ __launch_bounds__(256) void k_gred(const float* __restrict__ Gp, const float* __restrict__ sp,
                                              float* __restrict__ G, float* __restrict__ sv, int nch) {
  int blk = blockIdx.x, b = blockIdx.y, t = threadIdx.x;
  int idx = blk * 256 + t;
  float a = 0.f;
  for (int c = 0; c < nch; c++) a += Gp[(size_t)(b * nch + c) * 4096 + idx];
  G[(size_t)b * 4096 + idx] = a;
  if (blk == 0 && t < 64) {
    float s = 0.f;
    for (int c = 0; c < nch; c++) s += sp[(size_t)(b * nch + c) * 64 + t];
    sv[b * 64 + t] = s;
  }
}

// ---- per (head, batch): M = Wk_i^T G + bk_i(x)s ; Pm_i = Wq_i M ; Rp_i = bq_i^T M ----
__global__ __launch_bounds__(256) void k_heads2(const float* __restrict__ G, const float* __restrict__ sv,
                                                const float* __restrict__ Wq, const float* __restrict__ bq,
                                                const float* __restrict__ Wk, const float* __restrict__ bk,
                                                float* __restrict__ Pm, float* __restrict__ Rp) {
  int i = blockIdx.x, b = blockIdx.y, t = threadIdx.x;
  __shared__ __align__(16) float Gs[4096];
  __shared__ __align__(16) float Ms[4096];
  __shared__ __align__(16) float Wks[4096];
  __shared__ float WqsT[64 * 65];
  __shared__ float ssv[64];
  __shared__ float bqs[64];
  const float4* G4 = reinterpret_cast<const float4*>(G + (size_t)b * 4096);
#pragma unroll
  for (int k = 0; k < 4; k++) reinterpret_cast<float4*>(Gs)[t + k * 256] = G4[t + k * 256];
  const float* wkb = Wk + (size_t)i * 4096;
  for (int idx = t; idx < 4096; idx += 256) Wks[idx] = wkb[idx];
  const float* wqb = Wq + (size_t)i * 4096;
  for (int idx = t; idx < 4096; idx += 256) {
    int c = idx >> 6, k = idx & 63;
    WqsT[k * 65 + c] = wqb[idx];
  }
  if (t < 64) { ssv[t] = sv[b * 64 + t]; bqs[t] = bq[i * 64 + t]; }
  __syncthreads();

  int kk = t >> 2, qb = (t & 3) * 16;
  float bkv = bk[i * 64 + kk];
  float4 acc[4];
#pragma unroll
  for (int u = 0; u < 4; u++) {
    acc[u].x = bkv * ssv[qb + u * 4 + 0];
    acc[u].y = bkv * ssv[qb + u * 4 + 1];
    acc[u].z = bkv * ssv[qb + u * 4 + 2];
    acc[u].w = bkv * ssv[qb + u * 4 + 3];
  }
  for (int c = 0; c < 64; c++) {
    float wv = Wks[c * 64 + kk];
    const float4* gr = reinterpret_cast<const float4*>(&Gs[c * 64 + qb]);
#pragma unroll
    for (int u = 0; u < 4; u++) {
      float4 gv = gr[u];
      acc[u].x += wv * gv.x; acc[u].y += wv * gv.y; acc[u].z += wv * gv.z; acc[u].w += wv * gv.w;
    }
  }
#pragma unroll
  for (int u = 0; u < 4; u++) reinterpret_cast<float4*>(&Ms[kk * 64 + qb])[u] = acc[u];
  __syncthreads();
  float4 acc2[4] = {};
  for (int k2 = 0; k2 < 64; k2++) {
    float wv = WqsT[k2 * 65 + kk];
    const float4* mr = reinterpret_cast<const float4*>(&Ms[k2 * 64 + qb]);
#pragma unroll
    for (int u = 0; u < 4; u++) {
      float4 mv = mr[u];
      acc2[u].x += wv * mv.x; acc2[u].y += wv * mv.y; acc2[u].z += wv * mv.z; acc2[u].w += wv * mv.w;
    }
  }
  float* po = Pm + (size_t)(b * RH + i) * 4096 + kk * 64 + qb;
#pragma unroll
  for (int u = 0; u < 4; u++) reinterpret_cast<float4*>(po)[u] = acc2[u];
  if (t < 64) {
    float a = 0.f;
    for (int k2 = 0; k2 < 64; k2++) a += bqs[k2] * Ms[k2 * 64 + t];
    Rp[(b * RH + i) * 64 + t] = a;
  }
}

// ---- mid = V @ (scale*sum_i Pm_i) + 1 (scale*sum_i Rp_i)^T, fused LN partials ----
__global__ __launch_bounds__(256) void k_mid(const float* __restrict__ V, const float* __restrict__ Pm,
                                             const float* __restrict__ Rp, float* __restrict__ mid,
                                             float* __restrict__ lnp, float scale) {
  int blk = blockIdx.x, b = blockIdx.y, t = threadIdx.x;
  __shared__ __align__(16) float As[4096];
  __shared__ float rs[64];
  const float4* P4 = reinterpret_cast<const float4*>(Pm + (size_t)b * RH * 4096);
#pragma unroll
  for (int k = 0; k < 4; k++) {
    int idx = t + k * 256;
    float4 a0 = P4[idx], a1 = P4[idx + 1024], a2 = P4[idx + 2048], a3 = P4[idx + 3072];
    float4 r;
    r.x = scale * (a0.x + a1.x + a2.x + a3.x);
    r.y = scale * (a0.y + a1.y + a2.y + a3.y);
    r.z = scale * (a0.z + a1.z + a2.z + a3.z);
    r.w = scale * (a0.w + a1.w + a2.w + a3.w);
    reinterpret_cast<float4*>(As)[idx] = r;
  }
  if (t < 64) {
    const float* rp = Rp + (size_t)b * RH * 64;
    rs[t] = scale * (rp[t] + rp[t + 64] + rp[t + 128] + rp[t + 192]);
  }
  __syncthreads();
  int row = blk * 64 + (t >> 2), qb = (t & 3) * 16;
  const float* vr = V + (size_t)b * 131072 + (size_t)row * 64;
  float4 acc[4];
#pragma unroll
  for (int u = 0; u < 4; u++) {
    acc[u].x = rs[qb + u * 4 + 0]; acc[u].y = rs[qb + u * 4 + 1];
    acc[u].z = rs[qb + u * 4 + 2]; acc[u].w = rs[qb + u * 4 + 3];
  }
  for (int c = 0; c < 64; c++) {
    float vv = vr[c];
    const float4* ar = reinterpret_cast<const float4*>(&As[c * 64 + qb]);
#pragma unroll
    for (int u = 0; u < 4; u++) {
      float4 av = ar[u];
      acc[u].x += vv * av.x; acc[u].y += vv * av.y; acc[u].z += vv * av.z; acc[u].w += vv * av.w;
    }
  }
  float* mo = mid + (size_t)b * 131072 + (size_t)row * 64 + qb;
#pragma unroll
  for (int u = 0; u < 4; u++) reinterpret_cast<float4*>(mo)[u] = acc[u];
  float s = 0.f, q = 0.f;
#pragma unroll
  for (int u = 0; u < 4; u++) {
    s += acc[u].x + acc[u].y + acc[u].z + acc[u].w;
    q += acc[u].x * acc[u].x + acc[u].y * acc[u].y + acc[u].z * acc[u].z + acc[u].w * acc[u].w;
  }
  for (int off = 32; off; off >>= 1) { s += __shfl_down(s, off); q += __shfl_down(q, off); }
  __shared__ float ss[4], qq[4];
  int lane = t & 63, wid = t >> 6;
  if (lane == 0) { ss[wid] = s; qq[wid] = q; }
  __syncthreads();
  if (t == 0) {
    lnp[(size_t)(b * 32 + blk) * 2] = ss[0] + ss[1] + ss[2] + ss[3];
    lnp[(size_t)(b * 32 + blk) * 2 + 1] = qq[0] + qq[1] + qq[2] + qq[3];
  }
}

// ---- k_y: ZT[b*64+q][z*1024+m] = bf16( sum_c V[b][z*1024+m][c] * (sum_i Pm_i)[c][q] ) ----
__global__ __launch_bounds__(256) void k_y(const float* __restrict__ V, const float* __restrict__ Pm,
                                           ushort* __restrict__ ZT) {
  int blk = blockIdx.x, b = blockIdx.y, z = blockIdx.z, t = threadIdx.x;
  __shared__ __align__(16) float As[4096];
  const float4* P4 = reinterpret_cast<const float4*>(Pm + (size_t)b * RH * 4096);
#pragma unroll
  for (int k = 0; k < 4; k++) {
    int idx = t + k * 256;
    float4 a0 = P4[idx], a1 = P4[idx + 1024], a2 = P4[idx + 2048], a3 = P4[idx + 3072];
    float4 r;
    r.x = a0.x + a1.x + a2.x + a3.x;
    r.y = a0.y + a1.y + a2.y + a3.y;
    r.z = a0.z + a1.z + a2.z + a3.z;
    r.w = a0.w + a1.w + a2.w + a3.w;
    reinterpret_cast<float4*>(As)[idx] = r;
  }
  __syncthreads();
  int m = blk * 32 + (t >> 3), qb = (t & 7) * 8;
  const float* vr = V + (size_t)b * 131072 + (size_t)(z * 1024 + m) * 64;
  float4 acc[2] = {};
  for (int c = 0; c < 64; c++) {
    float vv = vr[c];
    const float4* ar = reinterpret_cast<const float4*>(&As[c * 64 + qb]);
#pragma unroll
    for (int u = 0; u < 2; u++) {
      float4 av = ar[u];
      acc[u].x += vv * av.x; acc[u].y += vv * av.y; acc[u].z += vv * av.z; acc[u].w += vv * av.w;
    }
  }
  ushort* zp = ZT + (size_t)(b * 64 + qb) * 2048 + (size_t)z * 1024 + m;
  zp[0 * 2048] = f2bf(acc[0].x); zp[1 * 2048] = f2bf(acc[0].y);
  zp[2 * 2048] = f2bf(acc[0].z); zp[3 * 2048] = f2bf(acc[0].w);
  zp[4 * 2048] = f2bf(acc[1].x); zp[5 * 2048] = f2bf(acc[1].y);
  zp[6 * 2048] = f2bf(acc[1].z); zp[7 * 2048] = f2bf(acc[1].w);
}

// ---- bf16 transpose: dst[c][colOff + r] = src[r][c]; src [1024][1024] bf16 ----
__global__ __launch_bounds__(256) void k_cvtTb(const ushort* __restrict__ srcA, const ushort* __restrict__ srcB,
                                               ushort* __restrict__ dst) {
  __shared__ float T[64][65];
  const ushort* src = blockIdx.z ? srcB : srcA;
  int colOff = blockIdx.z ? 1024 : 0;
  int t = threadIdx.x;
  int c0 = blockIdx.x * 64, r0 = blockIdx.y * 64;
  int rr = t >> 2, cc = (t & 3) * 16;
  const uint4* s4 = reinterpret_cast<const uint4*>(src + (size_t)(r0 + rr) * 1024 + c0 + cc);
  uint4 q0 = s4[0], q1 = s4[1];
  uint qs[8] = {q0.x, q0.y, q0.z, q0.w, q1.x, q1.y, q1.z, q1.w};
#pragma unroll
  for (int j = 0; j < 8; j++) {
    T[rr][cc + 2 * j]     = bf2f((ushort)(qs[j] & 0xffffu));
    T[rr][cc + 2 * j + 1] = bf2f((ushort)(qs[j] >> 16));
  }
  __syncthreads();
  uint pk[8];
#pragma unroll
  for (int j = 0; j < 8; j++) {
    uint lo = (uint)f2bf(T[cc + 2 * j][rr]);
    uint hi = (uint)f2bf(T[cc + 2 * j + 1][rr]);
    pk[j] = lo | (hi << 16);
  }
  ushort* dp = dst + (size_t)(c0 + rr) * 2048 + colOff + r0 + cc;
  uint4* dp4 = reinterpret_cast<uint4*>(dp);
  dp4[0] = make_uint4(pk[0], pk[1], pk[2], pk[3]);
  dp4[1] = make_uint4(pk[4], pk[5], pk[6], pk[7]);
}

// ---- MFMA final GEMM: P_kz[n][bi] = sum_{K in kz quarter} WT[n][K] * ZT[bi][K] ----
// 32n x 64bi per block; 4 waves of 16n x 32bi; direct 16B global fragment loads.
__global__ __launch_bounds__(256) void k_final_mfma(const ushort* __restrict__ WT,
                                                    const ushort* __restrict__ ZT,
                                                    float* __restrict__ P0, float* __restrict__ P1,
                                                    float* __restrict__ P2, float* __restrict__ P3) {
  int tn = blockIdx.x, tb = blockIdx.y, kz = blockIdx.z, t = threadIdx.x;
  int lane = t & 63, w = t >> 6;
  int wn = w & 1, wb = w >> 1;
  int r = lane & 15, g = lane >> 4;
  int nrow = tn * 32 + wn * 16 + r;
  int bi0 = tb * 64 + wb * 32 + r;
  const ushort* wp = WT + (size_t)nrow * 2048 + kz * 512 + g * 8;
  const ushort* zp0 = ZT + (size_t)bi0 * 2048 + kz * 512 + g * 8;
  const ushort* zp1 = zp0 + 16 * 2048;
  f32x4 a0 = {0.f, 0.f, 0.f, 0.f}, a1 = a0;
#pragma unroll 4
  for (int ks = 0; ks < 512; ks += 32) {
    bf16x8 fa  = *reinterpret_cast<const bf16x8*>(wp + ks);
    bf16x8 fb0 = *reinterpret_cast<const bf16x8*>(zp0 + ks);
    bf16x8 fb1 = *reinterpret_cast<const bf16x8*>(zp1 + ks);
    a0 = __builtin_amdgcn_mfma_f32_16x16x32_bf16(fa, fb0, a0, 0, 0, 0);
    a1 = __builtin_amdgcn_mfma_f32_16x16x32_bf16(fa, fb1, a1, 0, 0, 0);
  }
  float* P = kz == 0 ? P0 : kz == 1 ? P1 : kz == 2 ? P2 : P3;
  int nbase = tn * 32 + wn * 16 + g * 4;
  int bib = tb * 64 + wb * 32 + r;
#pragma unroll
  for (int rr = 0; rr < 4; rr++) {
    P[(size_t)(nbase + rr) * 512 + bib]      = a0[rr];
    P[(size_t)(nbase + rr) * 512 + bib + 16] = a1[rr];
  }
}

// ---- out = CFINAL * (P0+P1+P2+P3 + w1[n]*(sum_i Rp_i)[b][i']) ----
__global__ __launch_bounds__(256) void k_final_red(const float* __restrict__ P0, const float* __restrict__ P1,
                                                   const float* __restrict__ P2, const float* __restrict__ P3,
                                                   const float* __restrict__ w1,
                                                   const float* __restrict__ Rp, float* __restrict__ out) {
  int idx4 = blockIdx.x * 256 + threadIdx.x;  // 0..131071 (float4 over out)
  int i4p = idx4 & 15;
  int n = (idx4 >> 4) & 1023;
  int b = idx4 >> 14;
  int pidx = n * 128 + b * 16 + i4p;           // float4 index into P[1024][512]
  float4 a0 = reinterpret_cast<const float4*>(P0)[pidx];
  float4 a1 = reinterpret_cast<const float4*>(P1)[pidx];
  float4 a2 = reinterpret_cast<const float4*>(P2)[pidx];
  float4 a3 = reinterpret_cast<const float4*>(P3)[pidx];
  const float4* R4 = reinterpret_cast<const float4*>(Rp + (size_t)b * RH * 64);
  float4 d0 = R4[i4p], d1 = R4[i4p + 16], d2 = R4[i4p + 32], d3 = R4[i4p + 48];
  float4 d;
  d.x = d0.x + d1.x + d2.x + d3.x;
  d.y = d0.y + d1.y + d2.y + d3.y;
  d.z = d0.z + d1.z + d2.z + d3.z;
  d.w = d0.w + d1.w + d2.w + d3.w;
  float wv = w1[n];
  float4 r;
  r.x = CFINAL * (a0.x + a1.x + a2.x + a3.x + wv * d.x);
  r.y = CFINAL * (a0.y + a1.y + a2.y + a3.y + wv * d.y);
  r.z = CFINAL * (a0.z + a1.z + a2.z + a3.z + wv * d.z);
  r.w = CFINAL * (a0.w + a1.w + a2.w + a3.w + wv * d.w);
  reinterpret_cast<float4*>(out)[idx4] = r;
}

extern "C" void kernel_launch(void* const* d_in, const int* in_sizes, int n_in,
                              void* d_out, int out_size, void* d_ws, size_t ws_size,
                              hipStream_t stream) {
  (void)in_sizes; (void)n_in; (void)out_size;
  const float* xy  = (const float*)d_in[1];
  const float* kW1 = (const float*)d_in[3];
  const float* kb1 = (const float*)d_in[4];
  const float* kW2 = (const float*)d_in[5];
  const float* kb2 = (const float*)d_in[6];
  const float* kW3 = (const float*)d_in[7];
  const float* kb3 = (const float*)d_in[8];
  const float* fW1 = (const float*)d_in[9];
  const float* fb1 = (const float*)d_in[10];
  const float* fW2 = (const float*)d_in[11];
  const float* fb2 = (const float*)d_in[12];
  const float* fW3 = (const float*)d_in[13];
  const float* fb3 = (const float*)d_in[14];
  const float* Wq  = (const float*)d_in[15];
  const float* bq  = (const float*)d_in[16];
  const float* Wk  = (const float*)d_in[17];
  const float* bk  = (const float*)d_in[18];
  const float* lng = (const float*)d_in[19];
  const float* lnb = (const float*)d_in[20];
  float* ws = (float*)d_ws;
  float* out = (float*)d_out;
  if (ws_size < WS_FLOATS * sizeof(float)) return;  // visible failure, no OOB

  float* V   = ws + OFF_V;
  float* MID = ws + OFF_MID;
  float* U1K = ws + OFF_U1K;
  float* U2K = ws + OFF_U2K;
  float* U1F = ws + OFF_U1F;
  float* U2F = ws + OFF_U2F;
  float* GP  = ws + OFF_GP;
  float* SP  = ws + OFF_SP;
  float* LNP = ws + OFF_LNP;
  float* W1v = ws + OFF_W1;
  float* CS  = ws + OFF_CS;
  // overlays (temporally disjoint with original owners)
  float* G    = ws + OFF_U1K;            // 32768 (U tables dead after k_mlp2)
  float* SV   = ws + OFF_U1F;            // 512
  float* PM   = ws + OFF_GP + 524288;    // 131072 (upper half of GP; GP dead after k_gred)
  float* RP   = ws + OFF_SP;             // 2048  (SP dead after k_gred)
  ushort* Wbf  = (ushort*)(ws + OFF_W);  // 1024x1024 bf16 (2MB of 4MB region)
  ushort* Wfbf = (ushort*)(ws + OFF_WF);
  ushort* WbfT = (ushort*)(ws + OFF_V);  // 1024x2048 bf16 (V dead after k_y)
  ushort* ZT   = (ushort*)(ws + OFF_MID);// 512x2048 bf16 (MID dead after j-loop)
  float* P0   = ws + OFF_GP;             // 524288 floats each
  float* P1   = ws + OFF_GP + 524288;
  float* P2   = ws + OFF_MID + 524288;   // MID upper half (lower holds ZT)
  float* P3   = ws + OFF_ZU;             // f32 Z region now unused

  k_pre_u<<<dim3(4), dim3(256), 0, stream>>>(kW1, kb1, fW1, fb1, U1K, U2K, U1F, U2F);
  k_mlp2<<<dim3(1024, 2), dim3(256), 0, stream>>>(U1K, U2K, kW2, kb2, kW3, kb3,
                                                  U1F, U2F, fW2, fb2, fW3, fb3, Wbf, Wfbf);
  k_colsum_p1<<<dim3(4, 16), dim3(256), 0, stream>>>(Wbf, Wfbf, CS);
  k_colsum_p2<<<dim3(4), dim3(256), 0, stream>>>(CS, W1v);

  k_redsum<<<dim3(32, 8), dim3(256), 0, stream>>>(xy, LNP);
  k_apply<<<dim3(1024), dim3(256), 0, stream>>>(xy, lng, lnb, LNP, nullptr, V);

  for (int j = 0; j < 2; j++) {
    k_xty<<<dim3(32, 8, 2), dim3(256), 0, stream>>>(V, V, GP, SP);
    k_gred<<<dim3(16, 8), dim3(256), 0, stream>>>(GP, SP, G, SV, 32);
    k_heads2<<<dim3(RH, 8), dim3(256), 0, stream>>>(G, SV, Wq + (size_t)j * RH * 4096, bq + j * RH * 64,
                                                    Wk + (size_t)j * RH * 4096, bk + j * RH * 64, PM, RP);
    k_mid<<<dim3(32, 8), dim3(256), 0, stream>>>(V, PM, RP, MID, LNP, DXDYf * SCALEf);
    k_apply<<<dim3(1024), dim3(256), 0, stream>>>(MID, lng + (size_t)(j + 1) * 131072,
                                                  lnb + (size_t)(j + 1) * 131072, LNP, V, V);
  }

  // final block: H = V_u^T xy_d, t = colsum(xy_d)
  k_xty<<<dim3(16, 8, 2), dim3(256), 0, stream>>>(V, xy, GP, SP);
  k_gred<<<dim3(16, 8), dim3(256), 0, stream>>>(GP, SP, G, SV, 16);
  k_heads2<<<dim3(RH, 8), dim3(256), 0, stream>>>(G, SV, Wq + (size_t)2 * RH * 4096, bq + 2 * RH * 64,
                                                  Wk + (size_t)2 * RH * 4096, bk + 2 * RH * 64, PM, RP);
  k_y<<<dim3(32, 8, 2), dim3(256), 0, stream>>>(V, PM, ZT);     // ZT bf16 [512][2048]
  k_cvtTb<<<dim3(16, 16, 2), dim3(256), 0, stream>>>(Wbf, Wfbf, WbfT);
  k_final_mfma<<<dim3(32, 8, 4), dim3(256), 0, stream>>>(WbfT, ZT, P0, P1, P2, P3);
  k_final_red<<<dim3(512), dim3(256), 0, stream>>>(P0, P1, P2, P3, W1v, RP, out);
}

// Round 8
// 212.189 us; speedup vs baseline: 1.1039x; 1.1039x over previous
//
#include <hip/hip_runtime.h>

namespace {
constexpr int SD = 1024;           // D
constexpr int TD = 2048;           // 2D
constexpr int BATCH = 8;
constexpr int RH = 4;
constexpr float EPSc = 1e-5f;
constexpr float DXf = 2.0f / 31.0f;
constexpr float DXDYf = DXf * DXf;
constexpr float SCALEf = 0.125f;
constexpr float CFINAL = DXDYf * DXDYf * SCALEf;

// workspace offsets (floats)
constexpr size_t OFF_V   = 0;
constexpr size_t OFF_MID = OFF_V   + (size_t)BATCH * TD * 64;   // 1048576
constexpr size_t OFF_W   = OFF_MID + (size_t)BATCH * TD * 64;
constexpr size_t OFF_WF  = OFF_W   + (size_t)SD * SD;
constexpr size_t OFF_U1K = OFF_WF  + (size_t)SD * SD;
constexpr size_t OFF_U2K = OFF_U1K + SD * 32;
constexpr size_t OFF_U1F = OFF_U2K + SD * 32;
constexpr size_t OFF_U2F = OFF_U1F + SD * 32;
constexpr size_t OFF_GP  = OFF_U2F + SD * 32;                    // 8*32*4096
constexpr size_t OFF_SP  = OFF_GP  + (size_t)BATCH * 32 * 4096;  // 8*32*64
constexpr size_t OFF_A   = OFF_SP  + BATCH * 32 * 64;            // spare
constexpr size_t OFF_RV  = OFF_A   + BATCH * 4096;               // spare
constexpr size_t OFF_LNP = OFF_RV  + BATCH * 64;                 // 8*32*2
constexpr size_t OFF_ZU  = OFF_LNP + BATCH * 32 * 2;             // Ep partials; later P3
constexpr size_t OFF_ZF  = OFF_ZU  + (size_t)SD * 512;
constexpr size_t OFF_W1  = OFF_ZF  + (size_t)SD * 512;
constexpr size_t OFF_CS  = OFF_W1  + SD;
constexpr size_t WS_FLOATS = OFF_CS + 16 * SD;
// overlays:
//  G->U1K, SV->U1F, A->GP+524288, RV->SP
//  Wbf->OFF_W lo, WTW->OFF_W+524288; Wfbf->OFF_WF lo, WTF->OFF_WF+524288
//  ZT->MID lo; P0->GP, P1->GP+524288, P2->MID+524288, P3->ZU
//  Ep/fp/gp/cp -> OFF_ZU (dead before P3 written)
} // namespace

typedef __bf16 bf16x8 __attribute__((ext_vector_type(8)));
typedef float f32x4 __attribute__((ext_vector_type(4)));

__device__ __forceinline__ float leaky(float x) { return fmaxf(x, 0.01f * x); }
__device__ __forceinline__ float gxv(int i) { return -1.0f + (2.0f / 31.0f) * (float)i; }
__device__ __forceinline__ ushort f2bf(float x) { union { __bf16 b; ushort u; } v; v.b = (__bf16)x; return v.u; }
__device__ __forceinline__ float bf2f(ushort u) { return __uint_as_float(((uint)u) << 16); }

// ---- edge-MLP layer-1 factorization tables ----
__global__ void k_pre_u(const float* __restrict__ kW1, const float* __restrict__ kb1,
                        const float* __restrict__ fW1, const float* __restrict__ fb1,
                        float* __restrict__ u1k, float* __restrict__ u2k,
                        float* __restrict__ u1f, float* __restrict__ u2f) {
  int n = blockIdx.x * blockDim.x + threadIdx.x;
  if (n >= SD) return;
  float ga = gxv(n >> 5), gb = gxv(n & 31);
  for (int j = 0; j < 32; j++) {
    u1k[n * 32 + j] = ga * kW1[j] + gb * kW1[32 + j] + kb1[j];
    u2k[n * 32 + j] = gb * kW1[64 + j] + ga * kW1[96 + j];
    u1f[n * 32 + j] = ga * fW1[j] + gb * fW1[32 + j] + fb1[j];
    u2f[n * 32 + j] = gb * fW1[64 + j] + ga * fW1[96 + j];
  }
}

// ---- MFMA edge-MLP (swapped operands): D[o][m]; in-lane W3 dot; 2-shfl reduce; bf16 out ----
__global__ __launch_bounds__(256) void k_mlp2(
    const float* __restrict__ u1k, const float* __restrict__ u2k,
    const float* __restrict__ kW2, const float* __restrict__ kb2,
    const float* __restrict__ kW3, const float* __restrict__ kb3,
    const float* __restrict__ u1f, const float* __restrict__ u2f,
    const float* __restrict__ fW2, const float* __restrict__ fb2,
    const float* __restrict__ fW3, const float* __restrict__ fb3,
    ushort* __restrict__ outK, ushort* __restrict__ outF) {
  const int which = blockIdx.y;
  const float* u1 = which ? u1f : u1k;
  const float* u2 = which ? u2f : u2k;
  const float* W2 = which ? fW2 : kW2;
  const float* b2 = which ? fb2 : kb2;
  const float* W3 = which ? fW3 : kW3;
  const float* b3 = which ? fb3 : kb3;
  ushort* out = which ? outF : outK;

  const int t = threadIdx.x;
  const int lane = t & 63, wave = t >> 6;
  const int row = lane & 15, grp = lane >> 4;
  const int n = blockIdx.x;

  bf16x8 wfrag[4];
  float4 b2q[4], w3q[4];
#pragma unroll
  for (int tt = 0; tt < 4; tt++) {
#pragma unroll
    for (int i = 0; i < 8; i++) wfrag[tt][i] = (__bf16)W2[(grp * 8 + i) * 64 + tt * 16 + row];
    b2q[tt] = *reinterpret_cast<const float4*>(b2 + tt * 16 + grp * 4);
    w3q[tt] = *reinterpret_cast<const float4*>(W3 + tt * 16 + grp * 4);
  }
  float u1j[8];
#pragma unroll
  for (int i = 0; i < 8; i++) u1j[i] = u1[n * 32 + grp * 8 + i];
  const float b3v = b3[0];
  const size_t outbase = (size_t)n * SD;

#pragma unroll
  for (int chunk = 0; chunk < 4; chunk++) {
#pragma unroll
    for (int st = 0; st < 4; st++) {
      int mbase = chunk * 256 + wave * 64 + st * 16;
      int m = mbase + row;
      const float4* u2p = reinterpret_cast<const float4*>(u2 + (size_t)m * 32 + grp * 8);
      float4 ua = u2p[0], ub = u2p[1];
      float hv[8] = {ua.x, ua.y, ua.z, ua.w, ub.x, ub.y, ub.z, ub.w};
      bf16x8 pfrag;
#pragma unroll
      for (int i = 0; i < 8; i++) pfrag[i] = (__bf16)leaky(u1j[i] + hv[i]);
      float accv = 0.f;
#pragma unroll
      for (int tt = 0; tt < 4; tt++) {
        f32x4 ci = {b2q[tt].x, b2q[tt].y, b2q[tt].z, b2q[tt].w};
        f32x4 c = __builtin_amdgcn_mfma_f32_16x16x32_bf16(wfrag[tt], pfrag, ci, 0, 0, 0);
        accv += leaky(c[0]) * w3q[tt].x;
        accv += leaky(c[1]) * w3q[tt].y;
        accv += leaky(c[2]) * w3q[tt].z;
        accv += leaky(c[3]) * w3q[tt].w;
      }
      accv += __shfl_xor(accv, 16, 64);
      accv += __shfl_xor(accv, 32, 64);
      if (grp == 0) out[outbase + mbase + row] = f2bf(accv + b3v);
    }
  }
}

// ---- bf16 transpose: dstZ[c][r] = src[r][c]; src/dst [1024][1024] bf16 ----
__global__ __launch_bounds__(256) void k_cvtTb(const ushort* __restrict__ srcA, const ushort* __restrict__ srcB,
                                               ushort* __restrict__ dstA, ushort* __restrict__ dstB) {
  __shared__ float T[64][65];
  const ushort* src = blockIdx.z ? srcB : srcA;
  ushort* dst = blockIdx.z ? dstB : dstA;
  int t = threadIdx.x;
  int c0 = blockIdx.x * 64, r0 = blockIdx.y * 64;
  int rr = t >> 2, cc = (t & 3) * 16;
  const uint4* s4 = reinterpret_cast<const uint4*>(src + (size_t)(r0 + rr) * 1024 + c0 + cc);
  uint4 q0 = s4[0], q1 = s4[1];
  uint qs[8] = {q0.x, q0.y, q0.z, q0.w, q1.x, q1.y, q1.z, q1.w};
#pragma unroll
  for (int j = 0; j < 8; j++) {
    T[rr][cc + 2 * j]     = bf2f((ushort)(qs[j] & 0xffffu));
    T[rr][cc + 2 * j + 1] = bf2f((ushort)(qs[j] >> 16));
  }
  __syncthreads();
  uint pk[8];
#pragma unroll
  for (int j = 0; j < 8; j++) {
    uint lo = (uint)f2bf(T[cc + 2 * j][rr]);
    uint hi = (uint)f2bf(T[cc + 2 * j + 1][rr]);
    pk[j] = lo | (hi << 16);
  }
  ushort* dp = dst + (size_t)(c0 + rr) * 1024 + r0 + cc;
  uint4* dp4 = reinterpret_cast<uint4*>(dp);
  dp4[0] = make_uint4(pk[0], pk[1], pk[2], pk[3]);
  dp4[1] = make_uint4(pk[4], pk[5], pk[6], pk[7]);
}

// ---- w1[n] = rowsum(WTW[n]) + rowsum(WTF[n]) ----
__global__ __launch_bounds__(256) void k_colsumT(const ushort* __restrict__ WTW, const ushort* __restrict__ WTF,
                                                 float* __restrict__ w1) {
  int t = threadIdx.x;
  int n = blockIdx.x * 16 + (t >> 4), seg = t & 15;
  const uint4* pa = reinterpret_cast<const uint4*>(WTW + (size_t)n * 1024 + seg * 64);
  const uint4* pf = reinterpret_cast<const uint4*>(WTF + (size_t)n * 1024 + seg * 64);
  float s = 0.f;
#pragma unroll
  for (int q = 0; q < 8; q++) {
    uint4 va = pa[q], vf = pf[q];
    uint u[8] = {va.x, va.y, va.z, va.w, vf.x, vf.y, vf.z, vf.w};
#pragma unroll
    for (int j = 0; j < 8; j++) s += bf2f((ushort)(u[j] & 0xffffu)) + bf2f((ushort)(u[j] >> 16));
  }
  s += __shfl_xor(s, 1, 64);
  s += __shfl_xor(s, 2, 64);
  s += __shfl_xor(s, 4, 64);
  s += __shfl_xor(s, 8, 64);
  if (seg == 0) w1[n] = s;
}

// ---- head collapse precompute, per (head i, block j): Ep = Wq_i Wk_i^T, fp = Wq_i bk_i,
//      gp = Wk_i bq_i, cp = bq_i . bk_i ----
__global__ __launch_bounds__(256) void k_eprep(const float* __restrict__ Wq, const float* __restrict__ bq,
                                               const float* __restrict__ Wk, const float* __restrict__ bk,
                                               float* __restrict__ Ep, float* __restrict__ fp,
                                               float* __restrict__ gp, float* __restrict__ cp) {
  int i = blockIdx.x, j = blockIdx.y, t = threadIdx.x;
  int h = j * RH + i;
  __shared__ __align__(16) float Wqs[4096];
  __shared__ float Wks[64 * 65];
  __shared__ float bqs[64], bks[64];
  const float* wqb = Wq + (size_t)h * 4096;
  const float* wkb = Wk + (size_t)h * 4096;
  for (int idx = t; idx < 4096; idx += 256) {
    Wqs[idx] = wqb[idx];
    Wks[(idx >> 6) * 65 + (idx & 63)] = wkb[idx];
  }
  if (t < 64) { bqs[t] = bq[h * 64 + t]; bks[t] = bk[h * 64 + t]; }
  __syncthreads();
  int cpp = t & 63, cb = (t >> 6) * 16;
  float acc[16];
#pragma unroll
  for (int u = 0; u < 16; u++) acc[u] = 0.f;
  for (int k = 0; k < 64; k++) {
    float wkv = Wks[cpp * 65 + k];
#pragma unroll
    for (int u = 0; u < 16; u++) acc[u] += Wqs[(cb + u) * 64 + k] * wkv;
  }
  float* eo = Ep + (size_t)h * 4096;
#pragma unroll
  for (int u = 0; u < 16; u++) eo[(cb + u) * 64 + cpp] = acc[u];
  if (t < 64) {
    float f = 0.f, gg = 0.f;
    for (int k = 0; k < 64; k++) {
      f  += Wqs[t * 64 + k] * bks[k];
      gg += Wks[t * 65 + k] * bqs[k];
    }
    fp[h * 64 + t] = f;
    gp[h * 64 + t] = gg;
    float ca = bqs[t] * bks[t];
    ca += __shfl_xor(ca, 1, 64);
    ca += __shfl_xor(ca, 2, 64);
    ca += __shfl_xor(ca, 4, 64);
    ca += __shfl_xor(ca, 8, 64);
    ca += __shfl_xor(ca, 16, 64);
    ca += __shfl_xor(ca, 32, 64);
    if (t == 0) cp[h] = ca;
  }
}

// ---- per batch: A = scale*(E_j G + f_j (x) s), r = scale*(g_j^T G + c_j s^T) ----
__global__ __launch_bounds__(256) void k_headsA(const float* __restrict__ G, const float* __restrict__ sv,
                                                const float* __restrict__ Ep, const float* __restrict__ fp,
                                                const float* __restrict__ gp, const float* __restrict__ cp,
                                                int j, float scale,
                                                float* __restrict__ A, float* __restrict__ RV) {
  int b = blockIdx.x, t = threadIdx.x;
  __shared__ float Es[64 * 65];
  __shared__ __align__(16) float Gs[4096];
  __shared__ float ss[64], fs[64], gs[64];
  __shared__ float cj;
  const float* e0 = Ep + (size_t)(j * RH) * 4096;
  for (int idx = t; idx < 4096; idx += 256) {
    float e = e0[idx] + e0[idx + 4096] + e0[idx + 8192] + e0[idx + 12288];
    Es[(idx >> 6) * 65 + (idx & 63)] = e;
    Gs[idx] = G[(size_t)b * 4096 + idx];
  }
  if (t < 64) {
    ss[t] = sv[b * 64 + t];
    int h0 = j * RH * 64;
    fs[t] = fp[h0 + t] + fp[h0 + 64 + t] + fp[h0 + 128 + t] + fp[h0 + 192 + t];
    gs[t] = gp[h0 + t] + gp[h0 + 64 + t] + gp[h0 + 128 + t] + gp[h0 + 192 + t];
  }
  if (t == 0) cj = cp[j * RH] + cp[j * RH + 1] + cp[j * RH + 2] + cp[j * RH + 3];
  __syncthreads();
  int c = t >> 2, qb = (t & 3) * 16;
  float fv = fs[c];
  float4 acc[4];
#pragma unroll
  for (int u = 0; u < 4; u++) {
    acc[u].x = fv * ss[qb + u * 4 + 0];
    acc[u].y = fv * ss[qb + u * 4 + 1];
    acc[u].z = fv * ss[qb + u * 4 + 2];
    acc[u].w = fv * ss[qb + u * 4 + 3];
  }
  for (int cpv = 0; cpv < 64; cpv++) {
    float ev = Es[c * 65 + cpv];
    const float4* gr = reinterpret_cast<const float4*>(&Gs[cpv * 64 + qb]);
#pragma unroll
    for (int u = 0; u < 4; u++) {
      float4 gv = gr[u];
      acc[u].x += ev * gv.x; acc[u].y += ev * gv.y; acc[u].z += ev * gv.z; acc[u].w += ev * gv.w;
    }
  }
  float* ao = A + (size_t)b * 4096 + c * 64 + qb;
#pragma unroll
  for (int u = 0; u < 4; u++) {
    float4 v = acc[u];
    v.x *= scale; v.y *= scale; v.z *= scale; v.w *= scale;
    reinterpret_cast<float4*>(ao)[u] = v;
  }
  if (t < 64) {
    float r = cj * ss[t];
    for (int cpv = 0; cpv < 64; cpv++) r += gs[cpv] * Gs[cpv * 64 + t];
    RV[b * 64 + t] = r * scale;
  }
}

// ---- LN partial sums (per batch, 32 chunks of 4096) ----
__global__ __launch_bounds__(256) void k_redsum(const float* __restrict__ X, float* __restrict__ part) {
  int b = blockIdx.y, c = blockIdx.x, t = threadIdx.x;
  const float4* X4 = reinterpret_cast<const float4*>(X + (size_t)b * 131072 + (size_t)c * 4096);
  float s = 0.f, q = 0.f;
#pragma unroll
  for (int k = 0; k < 4; k++) {
    float4 v = X4[t + k * 256];
    s += v.x + v.y + v.z + v.w;
    q += v.x * v.x + v.y * v.y + v.z * v.z + v.w * v.w;
  }
  for (int off = 32; off; off >>= 1) { s += __shfl_down(s, off); q += __shfl_down(q, off); }
  __shared__ float ss[4], qq[4];
  int lane = t & 63, wid = t >> 6;
  if (lane == 0) { ss[wid] = s; qq[wid] = q; }
  __syncthreads();
  if (t == 0) {
    part[(size_t)(b * 32 + c) * 2] = ss[0] + ss[1] + ss[2] + ss[3];
    part[(size_t)(b * 32 + c) * 2 + 1] = qq[0] + qq[1] + qq[2] + qq[3];
  }
}

// ---- fused LN-apply + X^T Y partials ----
// block (c,b,zh): rows c*64..; apply LN (+addv) -> Vout (zh==0), stage in LDS;
// if c<nchG compute Gp q-half (zh) with Y = Yext rows or the applied values; sp on zh==0.
__global__ __launch_bounds__(256) void k_applyxty(
    const float* __restrict__ src, const float* __restrict__ g,
    const float* __restrict__ bb, const float* __restrict__ lnp,
    const float* __restrict__ addv, float* __restrict__ Vout,
    const float* __restrict__ Yext,
    float* __restrict__ Gp, float* __restrict__ sp, int nchG) {
  int c = blockIdx.x, b = blockIdx.y, zh = blockIdx.z, t = threadIdx.x;
  bool doG = (c < nchG);
  if (zh == 1 && !doG) return;
  __shared__ float sm[2];
  __shared__ __align__(16) float Xs[4096];
  __shared__ __align__(16) float Ys[4096];
  if (t == 0) {
    float s = 0.f, q = 0.f;
    for (int cc = 0; cc < 32; cc++) {
      s += lnp[(size_t)(b * 32 + cc) * 2];
      q += lnp[(size_t)(b * 32 + cc) * 2 + 1];
    }
    float mean = s / 131072.0f;
    sm[0] = mean;
    sm[1] = rsqrtf(q / 131072.0f - mean * mean + EPSc);
  }
  __syncthreads();
  float mean = sm[0], is = sm[1];
  size_t base4 = (size_t)b * 32768 + (size_t)c * 1024;  // float4 units
  const float4* src4 = reinterpret_cast<const float4*>(src);
  const float4* g4 = reinterpret_cast<const float4*>(g);
  const float4* bv4 = reinterpret_cast<const float4*>(bb);
  const float4* a4 = reinterpret_cast<const float4*>(addv);
  float4* v4 = reinterpret_cast<float4*>(Vout);
#pragma unroll
  for (int k = 0; k < 4; k++) {
    int idx = t + k * 256;
    int p4 = c * 1024 + idx;
    float4 v = src4[base4 + idx];
    float4 gg = g4[p4], bv = bv4[p4];
    float4 r;
    r.x = (v.x - mean) * is * gg.x + bv.x;
    r.y = (v.y - mean) * is * gg.y + bv.y;
    r.z = (v.z - mean) * is * gg.z + bv.z;
    r.w = (v.w - mean) * is * gg.w + bv.w;
    if (addv != nullptr) {
      float4 av = a4[base4 + idx];
      r.x += av.x; r.y += av.y; r.z += av.z; r.w += av.w;
    }
    if (zh == 0) v4[base4 + idx] = r;
    reinterpret_cast<float4*>(Xs)[idx] = r;
  }
  if (Yext != nullptr) {
    const float4* y4 = reinterpret_cast<const float4*>(Yext);
#pragma unroll
    for (int k = 0; k < 4; k++) {
      int idx = t + k * 256;
      reinterpret_cast<float4*>(Ys)[idx] = y4[base4 + idx];
    }
  }
  __syncthreads();
  if (!doG) return;
  const float* yp = (Yext != nullptr) ? Ys : Xs;
  int p = t >> 2, ql = zh * 32 + (t & 3) * 8;
  float4 acc[2] = {};
  for (int k2 = 0; k2 < 64; k2++) {
    float xv = Xs[k2 * 64 + p];
    const float4* y = reinterpret_cast<const float4*>(&yp[k2 * 64 + ql]);
#pragma unroll
    for (int u = 0; u < 2; u++) {
      float4 yv = y[u];
      acc[u].x += xv * yv.x; acc[u].y += xv * yv.y; acc[u].z += xv * yv.z; acc[u].w += xv * yv.w;
    }
  }
  float* go = Gp + (size_t)(b * nchG + c) * 4096 + p * 64 + ql;
#pragma unroll
  for (int u = 0; u < 2; u++) reinterpret_cast<float4*>(go)[u] = acc[u];
  if (zh == 0 && t < 64) {
    float ssum = 0.f;
    for (int k2 = 0; k2 < 64; k2++) ssum += yp[k2 * 64 + t];
    sp[(size_t)(b * nchG + c) * 64 + t] = ssum;
  }
}

// ---- coalesced partial reduction: G = sum_c Gp[c], sv = sum_c sp[c] ----
__global__ __launch_bounds__(256) void k_gred(const float* __restrict__ Gp, const float* __restrict__ sp,
                                              float* __restrict__ G, float* __restrict__ sv, int nch) {
  int blk = blockIdx.x, b = blockIdx.y, t = threadIdx.x;
  int idx = blk * 256 + t;
  float a = 0.f;
  for (int c = 0; c < nch; c++) a += Gp[(size_t)(b * nch + c) * 4096 + idx];
  G[(size_t)b * 4096 + idx] = a;
  if (blk == 0 && t < 64) {
    float s = 0.f;
    for (int c = 0; c < nch; c++) s += sp[(size_t)(b * nch + c) * 64 + t];
    sv[b * 64 + t] = s;
  }
}

// ---- mid = V @ A + 1 r^T (scale pre-folded into A/r), fused LN partials ----
__global__ __launch_bounds__(256) void k_mid(const float* __restrict__ V, const float* __restrict__ A,
                                             const float* __restrict__ RV, float* __restrict__ mid,
                                             float* __restrict__ lnp) {
  int blk = blockIdx.x, b = blockIdx.y, t = threadIdx.x;
  __shared__ __align__(16) float As[4096];
  __shared__ float rs[64];
  const float4* A4 = reinterpret_cast<const float4*>(A + (size_t)b * 4096);
#pragma unroll
  for (int k = 0; k < 4; k++) reinterpret_cast<float4*>(As)[t + k * 256] = A4[t + k * 256];
  if (t < 64) rs[t] = RV[b * 64 + t];
  __syncthreads();
  int row = blk * 64 + (t >> 2), qb = (t & 3) * 16;
  const float* vr = V + (size_t)b * 131072 + (size_t)row * 64;
  float4 acc[4];
#pragma unroll
  for (int u = 0; u < 4; u++) {
    acc[u].x = rs[qb + u * 4 + 0]; acc[u].y = rs[qb + u * 4 + 1];
    acc[u].z = rs[qb + u * 4 + 2]; acc[u].w = rs[qb + u * 4 + 3];
  }
  for (int c = 0; c < 64; c++) {
    float vv = vr[c];
    const float4* ar = reinterpret_cast<const float4*>(&As[c * 64 + qb]);
#pragma unroll
    for (int u = 0; u < 4; u++) {
      float4 av = ar[u];
      acc[u].x += vv * av.x; acc[u].y += vv * av.y; acc[u].z += vv * av.z; acc[u].w += vv * av.w;
    }
  }
  float* mo = mid + (size_t)b * 131072 + (size_t)row * 64 + qb;
#pragma unroll
  for (int u = 0; u < 4; u++) reinterpret_cast<float4*>(mo)[u] = acc[u];
  float s = 0.f, q = 0.f;
#pragma unroll
  for (int u = 0; u < 4; u++) {
    s += acc[u].x + acc[u].y + acc[u].z + acc[u].w;
    q += acc[u].x * acc[u].x + acc[u].y * acc[u].y + acc[u].z * acc[u].z + acc[u].w * acc[u].w;
  }
  for (int off = 32; off; off >>= 1) { s += __shfl_down(s, off); q += __shfl_down(q, off); }
  __shared__ float ss[4], qq[4];
  int lane = t & 63, wid = t >> 6;
  if (lane == 0) { ss[wid] = s; qq[wid] = q; }
  __syncthreads();
  if (t == 0) {
    lnp[(size_t)(b * 32 + blk) * 2] = ss[0] + ss[1] + ss[2] + ss[3];
    lnp[(size_t)(b * 32 + blk) * 2 + 1] = qq[0] + qq[1] + qq[2] + qq[3];
  }
}

// ---- k_y: ZT[b*64+q][z*1024+m] = bf16( sum_c V[b][z*1024+m][c] * A[c][q] ) ----
__global__ __launch_bounds__(256) void k_y(const float* __restrict__ V, const float* __restrict__ A,
                                           ushort* __restrict__ ZT) {
  int blk = blockIdx.x, b = blockIdx.y, z = blockIdx.z, t = threadIdx.x;
  __shared__ __align__(16) float As[4096];
  const float4* A4 = reinterpret_cast<const float4*>(A + (size_t)b * 4096);
#pragma unroll
  for (int k = 0; k < 4; k++) reinterpret_cast<float4*>(As)[t + k * 256] = A4[t + k * 256];
  __syncthreads();
  int m = blk * 32 + (t >> 3), qb = (t & 7) * 8;
  const float* vr = V + (size_t)b * 131072 + (size_t)(z * 1024 + m) * 64;
  float4 acc[2] = {};
  for (int c = 0; c < 64; c++) {
    float vv = vr[c];
    const float4* ar = reinterpret_cast<const float4*>(&As[c * 64 + qb]);
#pragma unroll
    for (int u = 0; u < 2; u++) {
      float4 av = ar[u];
      acc[u].x += vv * av.x; acc[u].y += vv * av.y; acc[u].z += vv * av.z; acc[u].w += vv * av.w;
    }
  }
  ushort* zp = ZT + (size_t)(b * 64 + qb) * 2048 + (size_t)z * 1024 + m;
  zp[0 * 2048] = f2bf(acc[0].x); zp[1 * 2048] = f2bf(acc[0].y);
  zp[2 * 2048] = f2bf(acc[0].z); zp[3 * 2048] = f2bf(acc[0].w);
  zp[4 * 2048] = f2bf(acc[1].x); zp[5 * 2048] = f2bf(acc[1].y);
  zp[6 * 2048] = f2bf(acc[1].z); zp[7 * 2048] = f2bf(acc[1].w);
}

// ---- MFMA final GEMM: P_kz[n][bi] over K quarter kz; WTW/WTF [1024][1024] bf16 ----
__global__ __launch_bounds__(256) void k_final_mfma(const ushort* __restrict__ WTW,
                                                    const ushort* __restrict__ WTF,
                                                    const ushort* __restrict__ ZT,
                                                    float* __restrict__ P0, float* __restrict__ P1,
                                                    float* __restrict__ P2, float* __restrict__ P3) {
  int tn = blockIdx.x, tb = blockIdx.y, kz = blockIdx.z, t = threadIdx.x;
  int lane = t & 63, w = t >> 6;
  int wn = w & 1, wb = w >> 1;
  int r = lane & 15, g = lane >> 4;
  int nrow = tn * 32 + wn * 16 + r;
  int bi0 = tb * 64 + wb * 32 + r;
  const ushort* wbase = (kz < 2) ? WTW : WTF;
  const ushort* wp = wbase + (size_t)nrow * 1024 + (kz & 1) * 512 + g * 8;
  const ushort* zp0 = ZT + (size_t)bi0 * 2048 + kz * 512 + g * 8;
  const ushort* zp1 = zp0 + 16 * 2048;
  f32x4 a0 = {0.f, 0.f, 0.f, 0.f}, a1 = a0;
#pragma unroll 4
  for (int ks = 0; ks < 512; ks += 32) {
    bf16x8 fa  = *reinterpret_cast<const bf16x8*>(wp + ks);
    bf16x8 fb0 = *reinterpret_cast<const bf16x8*>(zp0 + ks);
    bf16x8 fb1 = *reinterpret_cast<const bf16x8*>(zp1 + ks);
    a0 = __builtin_amdgcn_mfma_f32_16x16x32_bf16(fa, fb0, a0, 0, 0, 0);
    a1 = __builtin_amdgcn_mfma_f32_16x16x32_bf16(fa, fb1, a1, 0, 0, 0);
  }
  float* P = kz == 0 ? P0 : kz == 1 ? P1 : kz == 2 ? P2 : P3;
  int nbase = tn * 32 + wn * 16 + g * 4;
  int bib = tb * 64 + wb * 32 + r;
#pragma unroll
  for (int rr = 0; rr < 4; rr++) {
    P[(size_t)(nbase + rr) * 512 + bib]      = a0[rr];
    P[(size_t)(nbase + rr) * 512 + bib + 16] = a1[rr];
  }
}

// ---- out = CFINAL * (P0+P1+P2+P3 + w1[n]*RV[b][i']) ----
__global__ __launch_bounds__(256) void k_final_red(const float* __restrict__ P0, const float* __restrict__ P1,
                                                   const float* __restrict__ P2, const float* __restrict__ P3,
                                                   const float* __restrict__ w1,
                                                   const float* __restrict__ RV, float* __restrict__ out) {
  int idx4 = blockIdx.x * 256 + threadIdx.x;  // 0..131071 (float4 over out)
  int i4p = idx4 & 15;
  int n = (idx4 >> 4) & 1023;
  int b = idx4 >> 14;
  int pidx = n * 128 + b * 16 + i4p;
  float4 a0 = reinterpret_cast<const float4*>(P0)[pidx];
  float4 a1 = reinterpret_cast<const float4*>(P1)[pidx];
  float4 a2 = reinterpret_cast<const float4*>(P2)[pidx];
  float4 a3 = reinterpret_cast<const float4*>(P3)[pidx];
  float4 d = reinterpret_cast<const float4*>(RV + (size_t)b * 64)[i4p];
  float wv = w1[n];
  float4 r;
  r.x = CFINAL * (a0.x + a1.x + a2.x + a3.x + wv * d.x);
  r.y = CFINAL * (a0.y + a1.y + a2.y + a3.y + wv * d.y);
  r.z = CFINAL * (a0.z + a1.z + a2.z + a3.z + wv * d.z);
  r.w = CFINAL * (a0.w + a1.w + a2.w + a3.w + wv * d.w);
  reinterpret_cast<float4*>(out)[idx4] = r;
}

extern "C" void kernel_launch(void* const* d_in, const int* in_sizes, int n_in,
                              void* d_out, int out_size, void* d_ws, size_t ws_size,
                              hipStream_t stream) {
  (void)in_sizes; (void)n_in; (void)out_size;
  const float* xy  = (const float*)d_in[1];
  const float* kW1 = (const float*)d_in[3];
  const float* kb1 = (const float*)d_in[4];
  const float* kW2 = (const float*)d_in[5];
  const float* kb2 = (const float*)d_in[6];
  const float* kW3 = (const float*)d_in[7];
  const float* kb3 = (const float*)d_in[8];
  const float* fW1 = (const float*)d_in[9];
  const float* fb1 = (const float*)d_in[10];
  const float* fW2 = (const float*)d_in[11];
  const float* fb2 = (const float*)d_in[12];
  const float* fW3 = (const float*)d_in[13];
  const float* fb3 = (const float*)d_in[14];
  const float* Wq  = (const float*)d_in[15];
  const float* bq  = (const float*)d_in[16];
  const float* Wk  = (const float*)d_in[17];
  const float* bk  = (const float*)d_in[18];
  const float* lng = (const float*)d_in[19];
  const float* lnb = (const float*)d_in[20];
  float* ws = (float*)d_ws;
  float* out = (float*)d_out;
  if (ws_size < WS_FLOATS * sizeof(float)) return;  // visible failure, no OOB

  float* V   = ws + OFF_V;
  float* MID = ws + OFF_MID;
  float* U1K = ws + OFF_U1K;
  float* U2K = ws + OFF_U2K;
  float* U1F = ws + OFF_U1F;
  float* U2F = ws + OFF_U2F;
  float* GPb = ws + OFF_GP;
  float* SPb = ws + OFF_SP;
  float* LNP = ws + OFF_LNP;
  float* W1v = ws + OFF_W1;
  // overlays
  float* G    = ws + OFF_U1K;             // 32768 (U tables dead after k_mlp2)
  float* SV   = ws + OFF_U1F;             // 512
  float* A    = ws + OFF_GP + 524288;     // 32768 (GP upper; Gp dead after gred)
  float* RV   = ws + OFF_SP;              // 512
  ushort* Wbf  = (ushort*)(ws + OFF_W);              // 1024x1024 bf16
  ushort* WTW  = (ushort*)(ws + OFF_W + 524288);     // transposed
  ushort* Wfbf = (ushort*)(ws + OFF_WF);
  ushort* WTF  = (ushort*)(ws + OFF_WF + 524288);
  ushort* ZT   = (ushort*)(ws + OFF_MID);            // 512x2048 bf16 (MID dead after j-loop)
  float* Ep   = ws + OFF_ZU;              // 12x4096 E partials (dead before P3 write)
  float* Fp   = ws + OFF_ZU + 49152;      // 12x64
  float* Gpp  = ws + OFF_ZU + 49920;      // 12x64
  float* Cp   = ws + OFF_ZU + 50688;      // 12
  float* P0   = ws + OFF_GP;
  float* P1   = ws + OFF_GP + 524288;
  float* P2   = ws + OFF_MID + 524288;
  float* P3   = ws + OFF_ZU;

  k_pre_u<<<dim3(4), dim3(256), 0, stream>>>(kW1, kb1, fW1, fb1, U1K, U2K, U1F, U2F);
  k_mlp2<<<dim3(1024, 2), dim3(256), 0, stream>>>(U1K, U2K, kW2, kb2, kW3, kb3,
                                                  U1F, U2F, fW2, fb2, fW3, fb3, Wbf, Wfbf);
  k_cvtTb<<<dim3(16, 16, 2), dim3(256), 0, stream>>>(Wbf, Wfbf, WTW, WTF);
  k_colsumT<<<dim3(64), dim3(256), 0, stream>>>(WTW, WTF, W1v);
  k_eprep<<<dim3(RH, 3), dim3(256), 0, stream>>>(Wq, bq, Wk, bk, Ep, Fp, Gpp, Cp);

  k_redsum<<<dim3(32, 8), dim3(256), 0, stream>>>(xy, LNP);
  k_applyxty<<<dim3(32, 8, 2), dim3(256), 0, stream>>>(xy, lng, lnb, LNP, nullptr, V,
                                                       nullptr, GPb, SPb, 32);
  for (int j = 0; j < 2; j++) {
    k_gred<<<dim3(16, 8), dim3(256), 0, stream>>>(GPb, SPb, G, SV, 32);
    k_headsA<<<dim3(8), dim3(256), 0, stream>>>(G, SV, Ep, Fp, Gpp, Cp, j, DXDYf * SCALEf, A, RV);
    k_mid<<<dim3(32, 8), dim3(256), 0, stream>>>(V, A, RV, MID, LNP);
    k_applyxty<<<dim3(32, 8, 2), dim3(256), 0, stream>>>(
        MID, lng + (size_t)(j + 1) * 131072, lnb + (size_t)(j + 1) * 131072, LNP, V, V,
        (j == 1) ? xy : nullptr, GPb, SPb, (j == 1) ? 16 : 32);
  }
  k_gred<<<dim3(16, 8), dim3(256), 0, stream>>>(GPb, SPb, G, SV, 16);
  k_headsA<<<dim3(8), dim3(256), 0, stream>>>(G, SV, Ep, Fp, Gpp, Cp, 2, 1.0f, A, RV);
  k_y<<<dim3(32, 8, 2), dim3(256), 0, stream>>>(V, A, ZT);
  k_final_mfma<<<dim3(32, 8, 4), dim3(256), 0, stream>>>(WTW, WTF, ZT, P0, P1, P2, P3);
  k_final_red<<<dim3(512), dim3(256), 0, stream>>>(P0, P1, P2, P3, W1v, RV, out);
}

// Round 9
// 210.811 us; speedup vs baseline: 1.1112x; 1.0065x over previous
//
#include <hip/hip_runtime.h>

namespace {
constexpr int SD = 1024;           // D
constexpr int TD = 2048;           // 2D
constexpr int BATCH = 8;
constexpr int RH = 4;
constexpr float EPSc = 1e-5f;
constexpr float DXf = 2.0f / 31.0f;
constexpr float DXDYf = DXf * DXf;
constexpr float SCALEf = 0.125f;
constexpr float CFINAL = DXDYf * DXDYf * SCALEf;

// workspace offsets (floats)
constexpr size_t OFF_V   = 0;
constexpr size_t OFF_MID = OFF_V   + (size_t)BATCH * TD * 64;   // 1048576
constexpr size_t OFF_W   = OFF_MID + (size_t)BATCH * TD * 64;
constexpr size_t OFF_WF  = OFF_W   + (size_t)SD * SD;
constexpr size_t OFF_U1K = OFF_WF  + (size_t)SD * SD;
constexpr size_t OFF_U2K = OFF_U1K + SD * 32;
constexpr size_t OFF_U1F = OFF_U2K + SD * 32;
constexpr size_t OFF_U2F = OFF_U1F + SD * 32;
constexpr size_t OFF_GP  = OFF_U2F + SD * 32;                    // 8*32*4096
constexpr size_t OFF_SP  = OFF_GP  + (size_t)BATCH * 32 * 4096;  // 8*32*64
constexpr size_t OFF_A   = OFF_SP  + BATCH * 32 * 64;            // A matrix (8x4096)
constexpr size_t OFF_RV  = OFF_A   + BATCH * 4096;               // RV (8x64)
constexpr size_t OFF_LNP = OFF_RV  + BATCH * 64;                 // LNP; later STAT
constexpr size_t OFF_ZU  = OFF_LNP + BATCH * 32 * 2;             // Ep region; later P3
constexpr size_t OFF_ZF  = OFF_ZU  + (size_t)SD * 512;
constexpr size_t OFF_W1  = OFF_ZF  + (size_t)SD * 512;
constexpr size_t OFF_CS  = OFF_W1  + SD;
constexpr size_t WS_FLOATS = OFF_CS + 16 * SD;
// overlays:
//  G->U1K, SV->U1F  (U tables dead after k_mlp2)
//  Wbf->OFF_W lo, WTW->OFF_W+524288; Wfbf->OFF_WF lo, WTF->OFF_WF+524288
//  ZT->MID lo; P0->GP, P1->GP+524288, P2->MID+524288, P3->ZU
//  Ep/fp/gp/cp -> OFF_ZU (dead before P3 written); STAT->OFF_LNP (dead after apply0)
} // namespace

typedef __bf16 bf16x8 __attribute__((ext_vector_type(8)));
typedef float f32x4 __attribute__((ext_vector_type(4)));

__device__ __forceinline__ float leaky(float x) { return fmaxf(x, 0.01f * x); }
__device__ __forceinline__ float gxv(int i) { return -1.0f + (2.0f / 31.0f) * (float)i; }
__device__ __forceinline__ ushort f2bf(float x) { union { __bf16 b; ushort u; } v; v.b = (__bf16)x; return v.u; }
__device__ __forceinline__ float bf2f(ushort u) { return __uint_as_float(((uint)u) << 16); }

// ---- edge-MLP layer-1 factorization tables ----
__global__ void k_pre_u(const float* __restrict__ kW1, const float* __restrict__ kb1,
                        const float* __restrict__ fW1, const float* __restrict__ fb1,
                        float* __restrict__ u1k, float* __restrict__ u2k,
                        float* __restrict__ u1f, float* __restrict__ u2f) {
  int n = blockIdx.x * blockDim.x + threadIdx.x;
  if (n >= SD) return;
  float ga = gxv(n >> 5), gb = gxv(n & 31);
  for (int j = 0; j < 32; j++) {
    u1k[n * 32 + j] = ga * kW1[j] + gb * kW1[32 + j] + kb1[j];
    u2k[n * 32 + j] = gb * kW1[64 + j] + ga * kW1[96 + j];
    u1f[n * 32 + j] = ga * fW1[j] + gb * fW1[32 + j] + fb1[j];
    u2f[n * 32 + j] = gb * fW1[64 + j] + ga * fW1[96 + j];
  }
}

// ---- MFMA edge-MLP with exact leaky split: W3^T leaky(c) = .505(lin^T h1 + w3^T b2) + .495 sum w3|c| ----
__global__ __launch_bounds__(256) void k_mlp2(
    const float* __restrict__ u1k, const float* __restrict__ u2k,
    const float* __restrict__ kW2, const float* __restrict__ kb2,
    const float* __restrict__ kW3, const float* __restrict__ kb3,
    const float* __restrict__ u1f, const float* __restrict__ u2f,
    const float* __restrict__ fW2, const float* __restrict__ fb2,
    const float* __restrict__ fW3, const float* __restrict__ fb3,
    ushort* __restrict__ outK, ushort* __restrict__ outF) {
  const int which = blockIdx.y;
  const float* u1 = which ? u1f : u1k;
  const float* u2 = which ? u2f : u2k;
  const float* W2 = which ? fW2 : kW2;
  const float* b2 = which ? fb2 : kb2;
  const float* W3 = which ? fW3 : kW3;
  const float* b3 = which ? fb3 : kb3;
  ushort* out = which ? outF : outK;

  const int t = threadIdx.x;
  const int lane = t & 63, wave = t >> 6;
  const int row = lane & 15, grp = lane >> 4;
  const int n = blockIdx.x;

  bf16x8 wfrag[4];
  float4 b2q[4], w3q[4];
#pragma unroll
  for (int tt = 0; tt < 4; tt++) {
#pragma unroll
    for (int i = 0; i < 8; i++) wfrag[tt][i] = (__bf16)W2[(grp * 8 + i) * 64 + tt * 16 + row];
    b2q[tt] = *reinterpret_cast<const float4*>(b2 + tt * 16 + grp * 4);
    w3q[tt] = *reinterpret_cast<const float4*>(W3 + tt * 16 + grp * 4);
  }
  // lin[k] = sum_o W2[k][o] * W3[o], for this lane's k = grp*8+i
  float linp[8];
  {
    float w3r[4];
#pragma unroll
    for (int tt = 0; tt < 4; tt++) w3r[tt] = W3[tt * 16 + row];
#pragma unroll
    for (int i = 0; i < 8; i++) {
      float s = 0.f;
#pragma unroll
      for (int tt = 0; tt < 4; tt++) s += W2[(grp * 8 + i) * 64 + tt * 16 + row] * w3r[tt];
      s += __shfl_xor(s, 1, 64); s += __shfl_xor(s, 2, 64);
      s += __shfl_xor(s, 4, 64); s += __shfl_xor(s, 8, 64);
      linp[i] = s;
    }
  }
  float cst;
  {
    float s = 0.f;
#pragma unroll
    for (int tt = 0; tt < 4; tt++)
      s += b2q[tt].x * w3q[tt].x + b2q[tt].y * w3q[tt].y + b2q[tt].z * w3q[tt].z + b2q[tt].w * w3q[tt].w;
    s += __shfl_xor(s, 16, 64);
    s += __shfl_xor(s, 32, 64);
    cst = 0.505f * s + b3[0];
  }
  float u1j[8];
#pragma unroll
  for (int i = 0; i < 8; i++) u1j[i] = u1[n * 32 + grp * 8 + i];
  const size_t outbase = (size_t)n * SD;

#pragma unroll
  for (int chunk = 0; chunk < 4; chunk++) {
    float4 L0[4], L1[4];
#pragma unroll
    for (int st = 0; st < 4; st++) {
      int m = chunk * 256 + wave * 64 + st * 16 + row;
      const float4* u2p = reinterpret_cast<const float4*>(u2 + (size_t)m * 32 + grp * 8);
      L0[st] = u2p[0]; L1[st] = u2p[1];
    }
#pragma unroll
    for (int st = 0; st < 4; st++) {
      int mbase = chunk * 256 + wave * 64 + st * 16;
      float h1f[8];
      h1f[0] = leaky(u1j[0] + L0[st].x); h1f[1] = leaky(u1j[1] + L0[st].y);
      h1f[2] = leaky(u1j[2] + L0[st].z); h1f[3] = leaky(u1j[3] + L0[st].w);
      h1f[4] = leaky(u1j[4] + L1[st].x); h1f[5] = leaky(u1j[5] + L1[st].y);
      h1f[6] = leaky(u1j[6] + L1[st].z); h1f[7] = leaky(u1j[7] + L1[st].w);
      bf16x8 pfrag;
#pragma unroll
      for (int i = 0; i < 8; i++) pfrag[i] = (__bf16)h1f[i];
      float accLin = 0.f;
#pragma unroll
      for (int i = 0; i < 8; i++) accLin = fmaf(linp[i], h1f[i], accLin);
      float accAbs = 0.f;
#pragma unroll
      for (int tt = 0; tt < 4; tt++) {
        f32x4 ci = {b2q[tt].x, b2q[tt].y, b2q[tt].z, b2q[tt].w};
        f32x4 c = __builtin_amdgcn_mfma_f32_16x16x32_bf16(wfrag[tt], pfrag, ci, 0, 0, 0);
        accAbs = fmaf(fabsf(c[0]), w3q[tt].x, accAbs);
        accAbs = fmaf(fabsf(c[1]), w3q[tt].y, accAbs);
        accAbs = fmaf(fabsf(c[2]), w3q[tt].z, accAbs);
        accAbs = fmaf(fabsf(c[3]), w3q[tt].w, accAbs);
      }
      float red = 0.495f * accAbs + 0.505f * accLin;
      red += __shfl_xor(red, 16, 64);
      red += __shfl_xor(red, 32, 64);
      if (grp == 0) out[outbase + mbase + row] = f2bf(red + cst);
    }
  }
}

// ---- bf16 transpose ----
__global__ __launch_bounds__(256) void k_cvtTb(const ushort* __restrict__ srcA, const ushort* __restrict__ srcB,
                                               ushort* __restrict__ dstA, ushort* __restrict__ dstB) {
  __shared__ float T[64][65];
  const ushort* src = blockIdx.z ? srcB : srcA;
  ushort* dst = blockIdx.z ? dstB : dstA;
  int t = threadIdx.x;
  int c0 = blockIdx.x * 64, r0 = blockIdx.y * 64;
  int rr = t >> 2, cc = (t & 3) * 16;
  const uint4* s4 = reinterpret_cast<const uint4*>(src + (size_t)(r0 + rr) * 1024 + c0 + cc);
  uint4 q0 = s4[0], q1 = s4[1];
  uint qs[8] = {q0.x, q0.y, q0.z, q0.w, q1.x, q1.y, q1.z, q1.w};
#pragma unroll
  for (int j = 0; j < 8; j++) {
    T[rr][cc + 2 * j]     = bf2f((ushort)(qs[j] & 0xffffu));
    T[rr][cc + 2 * j + 1] = bf2f((ushort)(qs[j] >> 16));
  }
  __syncthreads();
  uint pk[8];
#pragma unroll
  for (int j = 0; j < 8; j++) {
    uint lo = (uint)f2bf(T[cc + 2 * j][rr]);
    uint hi = (uint)f2bf(T[cc + 2 * j + 1][rr]);
    pk[j] = lo | (hi << 16);
  }
  ushort* dp = dst + (size_t)(c0 + rr) * 1024 + r0 + cc;
  uint4* dp4 = reinterpret_cast<uint4*>(dp);
  dp4[0] = make_uint4(pk[0], pk[1], pk[2], pk[3]);
  dp4[1] = make_uint4(pk[4], pk[5], pk[6], pk[7]);
}

// ---- w1[n] = rowsum(WTW[n]) + rowsum(WTF[n]) ----
__global__ __launch_bounds__(256) void k_colsumT(const ushort* __restrict__ WTW, const ushort* __restrict__ WTF,
                                                 float* __restrict__ w1) {
  int t = threadIdx.x;
  int n = blockIdx.x * 16 + (t >> 4), seg = t & 15;
  const uint4* pa = reinterpret_cast<const uint4*>(WTW + (size_t)n * 1024 + seg * 64);
  const uint4* pf = reinterpret_cast<const uint4*>(WTF + (size_t)n * 1024 + seg * 64);
  float s = 0.f;
#pragma unroll
  for (int q = 0; q < 8; q++) {
    uint4 va = pa[q], vf = pf[q];
    uint u[8] = {va.x, va.y, va.z, va.w, vf.x, vf.y, vf.z, vf.w};
#pragma unroll
    for (int j = 0; j < 8; j++) s += bf2f((ushort)(u[j] & 0xffffu)) + bf2f((ushort)(u[j] >> 16));
  }
  s += __shfl_xor(s, 1, 64);
  s += __shfl_xor(s, 2, 64);
  s += __shfl_xor(s, 4, 64);
  s += __shfl_xor(s, 8, 64);
  if (seg == 0) w1[n] = s;
}

// ---- head collapse precompute ----
__global__ __launch_bounds__(256) void k_eprep(const float* __restrict__ Wq, const float* __restrict__ bq,
                                               const float* __restrict__ Wk, const float* __restrict__ bk,
                                               float* __restrict__ Ep, float* __restrict__ fp,
                                               float* __restrict__ gp, float* __restrict__ cp) {
  int i = blockIdx.x, j = blockIdx.y, t = threadIdx.x;
  int h = j * RH + i;
  __shared__ __align__(16) float Wqs[4096];
  __shared__ float Wks[64 * 65];
  __shared__ float bqs[64], bks[64];
  const float* wqb = Wq + (size_t)h * 4096;
  const float* wkb = Wk + (size_t)h * 4096;
  for (int idx = t; idx < 4096; idx += 256) {
    Wqs[idx] = wqb[idx];
    Wks[(idx >> 6) * 65 + (idx & 63)] = wkb[idx];
  }
  if (t < 64) { bqs[t] = bq[h * 64 + t]; bks[t] = bk[h * 64 + t]; }
  __syncthreads();
  int cpp = t & 63, cb = (t >> 6) * 16;
  float acc[16];
#pragma unroll
  for (int u = 0; u < 16; u++) acc[u] = 0.f;
  for (int k = 0; k < 64; k++) {
    float wkv = Wks[cpp * 65 + k];
#pragma unroll
    for (int u = 0; u < 16; u++) acc[u] += Wqs[(cb + u) * 64 + k] * wkv;
  }
  float* eo = Ep + (size_t)h * 4096;
#pragma unroll
  for (int u = 0; u < 16; u++) eo[(cb + u) * 64 + cpp] = acc[u];
  if (t < 64) {
    float f = 0.f, gg = 0.f;
    for (int k = 0; k < 64; k++) {
      f  += Wqs[t * 64 + k] * bks[k];
      gg += Wks[t * 65 + k] * bqs[k];
    }
    fp[h * 64 + t] = f;
    gp[h * 64 + t] = gg;
    float ca = bqs[t] * bks[t];
    ca += __shfl_xor(ca, 1, 64);
    ca += __shfl_xor(ca, 2, 64);
    ca += __shfl_xor(ca, 4, 64);
    ca += __shfl_xor(ca, 8, 64);
    ca += __shfl_xor(ca, 16, 64);
    ca += __shfl_xor(ca, 32, 64);
    if (t == 0) cp[h] = ca;
  }
}

// ---- LN partial sums over xy ----
__global__ __launch_bounds__(256) void k_redsum(const float* __restrict__ X, float* __restrict__ part) {
  int b = blockIdx.y, c = blockIdx.x, t = threadIdx.x;
  const float4* X4 = reinterpret_cast<const float4*>(X + (size_t)b * 131072 + (size_t)c * 4096);
  float s = 0.f, q = 0.f;
#pragma unroll
  for (int k = 0; k < 4; k++) {
    float4 v = X4[t + k * 256];
    s += v.x + v.y + v.z + v.w;
    q += v.x * v.x + v.y * v.y + v.z * v.z + v.w * v.w;
  }
  for (int off = 32; off; off >>= 1) { s += __shfl_down(s, off); q += __shfl_down(q, off); }
  __shared__ float ss[4], qq[4];
  int lane = t & 63, wid = t >> 6;
  if (lane == 0) { ss[wid] = s; qq[wid] = q; }
  __syncthreads();
  if (t == 0) {
    part[(size_t)(b * 32 + c) * 2] = ss[0] + ss[1] + ss[2] + ss[3];
    part[(size_t)(b * 32 + c) * 2 + 1] = qq[0] + qq[1] + qq[2] + qq[3];
  }
}

// ---- initial LN-apply (stats from LNP) + XtY 4x4-tile partials ----
__global__ __launch_bounds__(256) void k_apply0(
    const float* __restrict__ src, const float* __restrict__ g,
    const float* __restrict__ bb, const float* __restrict__ lnp,
    float* __restrict__ Vout, float* __restrict__ Gp, float* __restrict__ sp) {
  int c = blockIdx.x, b = blockIdx.y, t = threadIdx.x;
  __shared__ float sm[2];
  __shared__ __align__(16) float Vs[4096];
  if (t == 0) {
    float s = 0.f, q = 0.f;
    for (int cc = 0; cc < 32; cc++) {
      s += lnp[(size_t)(b * 32 + cc) * 2];
      q += lnp[(size_t)(b * 32 + cc) * 2 + 1];
    }
    float mean = s / 131072.0f;
    sm[0] = mean;
    sm[1] = rsqrtf(q / 131072.0f - mean * mean + EPSc);
  }
  __syncthreads();
  float mean = sm[0], is = sm[1];
  size_t base4 = (size_t)b * 32768 + (size_t)c * 1024;
#pragma unroll
  for (int k = 0; k < 4; k++) {
    int idx = t + k * 256;
    float4 v = reinterpret_cast<const float4*>(src)[base4 + idx];
    float4 gg = reinterpret_cast<const float4*>(g)[c * 1024 + idx];
    float4 bv = reinterpret_cast<const float4*>(bb)[c * 1024 + idx];
    float4 r;
    r.x = (v.x - mean) * is * gg.x + bv.x;
    r.y = (v.y - mean) * is * gg.y + bv.y;
    r.z = (v.z - mean) * is * gg.z + bv.z;
    r.w = (v.w - mean) * is * gg.w + bv.w;
    reinterpret_cast<float4*>(Vout)[base4 + idx] = r;
    reinterpret_cast<float4*>(Vs)[idx] = r;
  }
  __syncthreads();
  int tp = t >> 4, tq = t & 15;
  float a2[4][4] = {};
  for (int k = 0; k < 64; k++) {
    float4 xv = *reinterpret_cast<const float4*>(&Vs[k * 64 + tp * 4]);
    float4 yv = *reinterpret_cast<const float4*>(&Vs[k * 64 + tq * 4]);
    a2[0][0] += xv.x * yv.x; a2[0][1] += xv.x * yv.y; a2[0][2] += xv.x * yv.z; a2[0][3] += xv.x * yv.w;
    a2[1][0] += xv.y * yv.x; a2[1][1] += xv.y * yv.y; a2[1][2] += xv.y * yv.z; a2[1][3] += xv.y * yv.w;
    a2[2][0] += xv.z * yv.x; a2[2][1] += xv.z * yv.y; a2[2][2] += xv.z * yv.z; a2[2][3] += xv.z * yv.w;
    a2[3][0] += xv.w * yv.x; a2[3][1] += xv.w * yv.y; a2[3][2] += xv.w * yv.z; a2[3][3] += xv.w * yv.w;
  }
  float* go = Gp + (size_t)(b * 32 + c) * 4096;
#pragma unroll
  for (int i = 0; i < 4; i++) {
    float4 w = {a2[i][0], a2[i][1], a2[i][2], a2[i][3]};
    *reinterpret_cast<float4*>(&go[(tp * 4 + i) * 64 + tq * 4]) = w;
  }
  if (t < 64) {
    float s = 0.f;
    for (int k = 0; k < 64; k++) s += Vs[k * 64 + t];
    sp[(size_t)(b * 32 + c) * 64 + t] = s;
  }
}

// ---- coalesced partial reduction: G = sum_c Gp[c], sv = sum_c sp[c] ----
__global__ __launch_bounds__(256) void k_gred(const float* __restrict__ Gp, const float* __restrict__ sp,
                                              float* __restrict__ G, float* __restrict__ sv, int nch) {
  int blk = blockIdx.x, b = blockIdx.y, t = threadIdx.x;
  int idx = blk * 256 + t;
  float a = 0.f;
  for (int c = 0; c < nch; c++) a += Gp[(size_t)(b * nch + c) * 4096 + idx];
  G[(size_t)b * 4096 + idx] = a;
  if (blk == 0 && t < 64) {
    float s = 0.f;
    for (int c = 0; c < nch; c++) s += sp[(size_t)(b * nch + c) * 64 + t];
    sv[b * 64 + t] = s;
  }
}

// ---- A = scale*(E_j G + f_j (x) s); r = scale*(g_j^T G + c_j s); analytic mid-LN stats ----
__global__ __launch_bounds__(256) void k_headsA2(
    const float* __restrict__ G, const float* __restrict__ sv,
    const float* __restrict__ Ep, const float* __restrict__ fp,
    const float* __restrict__ gp, const float* __restrict__ cp,
    int j, float scale, int doStats,
    float* __restrict__ A, float* __restrict__ RVo, float* __restrict__ STAT) {
  int b = blockIdx.x, t = threadIdx.x;
  __shared__ float Es[64 * 65];
  __shared__ __align__(16) float Gs[4096];
  __shared__ __align__(16) float As[4096];
  __shared__ float ss[64], fs[64], gs[64];
  __shared__ float cj;
  __shared__ float redbuf[8];
  const float* e0 = Ep + (size_t)(j * RH) * 4096;
  for (int idx = t; idx < 4096; idx += 256) {
    float e = e0[idx] + e0[idx + 4096] + e0[idx + 8192] + e0[idx + 12288];
    Es[(idx >> 6) * 65 + (idx & 63)] = e;
    Gs[idx] = G[(size_t)b * 4096 + idx];
  }
  if (t < 64) {
    ss[t] = sv[b * 64 + t];
    int h0 = j * RH * 64;
    fs[t] = fp[h0 + t] + fp[h0 + 64 + t] + fp[h0 + 128 + t] + fp[h0 + 192 + t];
    gs[t] = gp[h0 + t] + gp[h0 + 64 + t] + gp[h0 + 128 + t] + gp[h0 + 192 + t];
  }
  if (t == 0) cj = cp[j * RH] + cp[j * RH + 1] + cp[j * RH + 2] + cp[j * RH + 3];
  __syncthreads();
  int c = t >> 2, qb = (t & 3) * 16;
  float fv = fs[c];
  float4 acc[4];
#pragma unroll
  for (int u = 0; u < 4; u++) {
    acc[u].x = fv * ss[qb + u * 4 + 0];
    acc[u].y = fv * ss[qb + u * 4 + 1];
    acc[u].z = fv * ss[qb + u * 4 + 2];
    acc[u].w = fv * ss[qb + u * 4 + 3];
  }
  for (int d = 0; d < 64; d++) {
    float ev = Es[c * 65 + d];
    const float4* gr = reinterpret_cast<const float4*>(&Gs[d * 64 + qb]);
#pragma unroll
    for (int u = 0; u < 4; u++) {
      float4 gv = gr[u];
      acc[u].x += ev * gv.x; acc[u].y += ev * gv.y; acc[u].z += ev * gv.z; acc[u].w += ev * gv.w;
    }
  }
  float* ao = A + (size_t)b * 4096 + c * 64 + qb;
#pragma unroll
  for (int u = 0; u < 4; u++) {
    float4 v = acc[u];
    v.x *= scale; v.y *= scale; v.z *= scale; v.w *= scale;
    reinterpret_cast<float4*>(ao)[u] = v;
    *reinterpret_cast<float4*>(&As[c * 64 + qb + u * 4]) = v;
  }
  float rv_t = 0.f;
  if (t < 64) {
    float r = cj * ss[t];
    for (int d = 0; d < 64; d++) r += gs[d] * Gs[d * 64 + t];
    r *= scale;
    RVo[b * 64 + t] = r;
    rv_t = r;
  }
  if (!doStats) return;
  __syncthreads();  // As visible
  // H = G*As for this thread's (c, qb) chunk
  float4 h[4] = {};
  for (int d = 0; d < 64; d++) {
    float gvv = Gs[c * 64 + d];
    const float4* ar = reinterpret_cast<const float4*>(&As[d * 64 + qb]);
#pragma unroll
    for (int u = 0; u < 4; u++) {
      float4 av = ar[u];
      h[u].x += gvv * av.x; h[u].y += gvv * av.y; h[u].z += gvv * av.z; h[u].w += gvv * av.w;
    }
  }
  float tp_ = 0.f;
#pragma unroll
  for (int u = 0; u < 4; u++) {
    const float4* av = reinterpret_cast<const float4*>(&As[c * 64 + qb + u * 4]);
    float4 a = *av;
    tp_ += a.x * h[u].x + a.y * h[u].y + a.z * h[u].z + a.w * h[u].w;
  }
  tp_ += __shfl_xor(tp_, 1, 64);  tp_ += __shfl_xor(tp_, 2, 64);
  tp_ += __shfl_xor(tp_, 4, 64);  tp_ += __shfl_xor(tp_, 8, 64);
  tp_ += __shfl_xor(tp_, 16, 64); tp_ += __shfl_xor(tp_, 32, 64);
  if ((t & 63) == 0) redbuf[t >> 6] = tp_;
  if (t < 64) {
    float t1 = 0.f;
    for (int d = 0; d < 64; d++) t1 += ss[d] * As[d * 64 + t];
    float s1 = t1, sr = rv_t, sr2 = rv_t * rv_t, srt = rv_t * t1;
#pragma unroll
    for (int off = 1; off < 64; off <<= 1) {
      s1  += __shfl_xor(s1, off, 64);
      sr  += __shfl_xor(sr, off, 64);
      sr2 += __shfl_xor(sr2, off, 64);
      srt += __shfl_xor(srt, off, 64);
    }
    if (t == 0) { redbuf[4] = s1; redbuf[5] = sr; redbuf[6] = sr2; redbuf[7] = srt; }
  }
  __syncthreads();
  if (t == 0) {
    float tr = redbuf[0] + redbuf[1] + redbuf[2] + redbuf[3];
    float smid = redbuf[4] + 2048.0f * redbuf[5];
    float mu = smid / 131072.0f;
    float e2 = (tr + 2.0f * redbuf[7] + 2048.0f * redbuf[6]) / 131072.0f;
    STAT[b * 2] = mu;
    STAT[b * 2 + 1] = rsqrtf(e2 - mu * mu + EPSc);
  }
}

// ---- fused: mid = V A + 1 r^T; LN via analytic stats; +V residual; write V'; XtY partials ----
__global__ __launch_bounds__(256) void k_midapply(
    float* __restrict__ V, const float* __restrict__ A,
    const float* __restrict__ RVv, const float* __restrict__ STAT,
    const float* __restrict__ g, const float* __restrict__ bb,
    const float* __restrict__ Yext,
    float* __restrict__ Gp, float* __restrict__ sp, int nchG) {
  int blk = blockIdx.x, b = blockIdx.y, t = threadIdx.x;
  __shared__ __align__(16) float As[4096];
  __shared__ __align__(16) float Vs[4096];
  __shared__ __align__(16) float Ys[4096];
  __shared__ float rs[64];
  __shared__ float sm[2];
  const float4* A4 = reinterpret_cast<const float4*>(A + (size_t)b * 4096);
#pragma unroll
  for (int k = 0; k < 4; k++) reinterpret_cast<float4*>(As)[t + k * 256] = A4[t + k * 256];
  if (t < 64) rs[t] = RVv[b * 64 + t];
  if (t == 0) { sm[0] = STAT[b * 2]; sm[1] = STAT[b * 2 + 1]; }
  bool doG = (blk < nchG);
  if (Yext != nullptr && doG) {
    size_t yb = (size_t)b * 32768 + (size_t)blk * 1024;
#pragma unroll
    for (int k = 0; k < 4; k++)
      reinterpret_cast<float4*>(Ys)[t + k * 256] = reinterpret_cast<const float4*>(Yext)[yb + t + k * 256];
  }
  __syncthreads();
  float mu = sm[0], is = sm[1];
  int rl = t >> 2, qb = (t & 3) * 16;
  int row = blk * 64 + rl;
  float* vr = V + (size_t)b * 131072 + (size_t)row * 64;
  float4 acc[4];
#pragma unroll
  for (int u = 0; u < 4; u++) {
    acc[u].x = rs[qb + u * 4 + 0]; acc[u].y = rs[qb + u * 4 + 1];
    acc[u].z = rs[qb + u * 4 + 2]; acc[u].w = rs[qb + u * 4 + 3];
  }
  for (int c = 0; c < 64; c++) {
    float vv = vr[c];
    const float4* ar = reinterpret_cast<const float4*>(&As[c * 64 + qb]);
#pragma unroll
    for (int u = 0; u < 4; u++) {
      float4 av = ar[u];
      acc[u].x += vv * av.x; acc[u].y += vv * av.y; acc[u].z += vv * av.z; acc[u].w += vv * av.w;
    }
  }
  const float4* g4 = reinterpret_cast<const float4*>(g + (size_t)row * 64 + qb);
  const float4* b4 = reinterpret_cast<const float4*>(bb + (size_t)row * 64 + qb);
  const float4* vq = reinterpret_cast<const float4*>(vr + qb);
  float4* vo = reinterpret_cast<float4*>(vr + qb);
#pragma unroll
  for (int u = 0; u < 4; u++) {
    float4 gg = g4[u], bv = b4[u], av = vq[u];
    float4 r;
    r.x = (acc[u].x - mu) * is * gg.x + bv.x + av.x;
    r.y = (acc[u].y - mu) * is * gg.y + bv.y + av.y;
    r.z = (acc[u].z - mu) * is * gg.z + bv.z + av.z;
    r.w = (acc[u].w - mu) * is * gg.w + bv.w + av.w;
    vo[u] = r;
    *reinterpret_cast<float4*>(&Vs[rl * 64 + qb + u * 4]) = r;
  }
  __syncthreads();
  if (!doG) return;
  const float* Yp = (Yext != nullptr) ? Ys : Vs;
  int tp = t >> 4, tq = t & 15;
  float a2[4][4] = {};
  for (int k = 0; k < 64; k++) {
    float4 xv = *reinterpret_cast<const float4*>(&Vs[k * 64 + tp * 4]);
    float4 yv = *reinterpret_cast<const float4*>(&Yp[k * 64 + tq * 4]);
    a2[0][0] += xv.x * yv.x; a2[0][1] += xv.x * yv.y; a2[0][2] += xv.x * yv.z; a2[0][3] += xv.x * yv.w;
    a2[1][0] += xv.y * yv.x; a2[1][1] += xv.y * yv.y; a2[1][2] += xv.y * yv.z; a2[1][3] += xv.y * yv.w;
    a2[2][0] += xv.z * yv.x; a2[2][1] += xv.z * yv.y; a2[2][2] += xv.z * yv.z; a2[2][3] += xv.z * yv.w;
    a2[3][0] += xv.w * yv.x; a2[3][1] += xv.w * yv.y; a2[3][2] += xv.w * yv.z; a2[3][3] += xv.w * yv.w;
  }
  float* go = Gp + (size_t)(b * nchG + blk) * 4096;
#pragma unroll
  for (int i = 0; i < 4; i++) {
    float4 w = {a2[i][0], a2[i][1], a2[i][2], a2[i][3]};
    *reinterpret_cast<float4*>(&go[(tp * 4 + i) * 64 + tq * 4]) = w;
  }
  if (t < 64) {
    float s = 0.f;
    for (int k = 0; k < 64; k++) s += Yp[k * 64 + t];
    sp[(size_t)(b * nchG + blk) * 64 + t] = s;
  }
}

// ---- k_y: ZT[b*64+q][z*1024+m] = bf16( sum_c V[b][z*1024+m][c] * A[c][q] ) ----
__global__ __launch_bounds__(256) void k_y(const float* __restrict__ V, const float* __restrict__ A,
                                           ushort* __restrict__ ZT) {
  int blk = blockIdx.x, b = blockIdx.y, z = blockIdx.z, t = threadIdx.x;
  __shared__ __align__(16) float As[4096];
  const float4* A4 = reinterpret_cast<const float4*>(A + (size_t)b * 4096);
#pragma unroll
  for (int k = 0; k < 4; k++) reinterpret_cast<float4*>(As)[t + k * 256] = A4[t + k * 256];
  __syncthreads();
  int m = blk * 32 + (t >> 3), qb = (t & 7) * 8;
  const float* vr = V + (size_t)b * 131072 + (size_t)(z * 1024 + m) * 64;
  float4 acc[2] = {};
  for (int c = 0; c < 64; c++) {
    float vv = vr[c];
    const float4* ar = reinterpret_cast<const float4*>(&As[c * 64 + qb]);
#pragma unroll
    for (int u = 0; u < 2; u++) {
      float4 av = ar[u];
      acc[u].x += vv * av.x; acc[u].y += vv * av.y; acc[u].z += vv * av.z; acc[u].w += vv * av.w;
    }
  }
  ushort* zp = ZT + (size_t)(b * 64 + qb) * 2048 + (size_t)z * 1024 + m;
  zp[0 * 2048] = f2bf(acc[0].x); zp[1 * 2048] = f2bf(acc[0].y);
  zp[2 * 2048] = f2bf(acc[0].z); zp[3 * 2048] = f2bf(acc[0].w);
  zp[4 * 2048] = f2bf(acc[1].x); zp[5 * 2048] = f2bf(acc[1].y);
  zp[6 * 2048] = f2bf(acc[1].z); zp[7 * 2048] = f2bf(acc[1].w);
}

// ---- MFMA final GEMM ----
__global__ __launch_bounds__(256) void k_final_mfma(const ushort* __restrict__ WTW,
                                                    const ushort* __restrict__ WTF,
                                                    const ushort* __restrict__ ZT,
                                                    float* __restrict__ P0, float* __restrict__ P1,
                                                    float* __restrict__ P2, float* __restrict__ P3) {
  int tn = blockIdx.x, tb = blockIdx.y, kz = blockIdx.z, t = threadIdx.x;
  int lane = t & 63, w = t >> 6;
  int wn = w & 1, wb = w >> 1;
  int r = lane & 15, g = lane >> 4;
  int nrow = tn * 32 + wn * 16 + r;
  int bi0 = tb * 64 + wb * 32 + r;
  const ushort* wbase = (kz < 2) ? WTW : WTF;
  const ushort* wp = wbase + (size_t)nrow * 1024 + (kz & 1) * 512 + g * 8;
  const ushort* zp0 = ZT + (size_t)bi0 * 2048 + kz * 512 + g * 8;
  const ushort* zp1 = zp0 + 16 * 2048;
  f32x4 a0 = {0.f, 0.f, 0.f, 0.f}, a1 = a0;
#pragma unroll 4
  for (int ks = 0; ks < 512; ks += 32) {
    bf16x8 fa  = *reinterpret_cast<const bf16x8*>(wp + ks);
    bf16x8 fb0 = *reinterpret_cast<const bf16x8*>(zp0 + ks);
    bf16x8 fb1 = *reinterpret_cast<const bf16x8*>(zp1 + ks);
    a0 = __builtin_amdgcn_mfma_f32_16x16x32_bf16(fa, fb0, a0, 0, 0, 0);
    a1 = __builtin_amdgcn_mfma_f32_16x16x32_bf16(fa, fb1, a1, 0, 0, 0);
  }
  float* P = kz == 0 ? P0 : kz == 1 ? P1 : kz == 2 ? P2 : P3;
  int nbase = tn * 32 + wn * 16 + g * 4;
  int bib = tb * 64 + wb * 32 + r;
#pragma unroll
  for (int rr = 0; rr < 4; rr++) {
    P[(size_t)(nbase + rr) * 512 + bib]      = a0[rr];
    P[(size_t)(nbase + rr) * 512 + bib + 16] = a1[rr];
  }
}

// ---- out = CFINAL * (P0+P1+P2+P3 + w1[n]*RV[b][i']) ----
__global__ __launch_bounds__(256) void k_final_red(const float* __restrict__ P0, const float* __restrict__ P1,
                                                   const float* __restrict__ P2, const float* __restrict__ P3,
                                                   const float* __restrict__ w1,
                                                   const float* __restrict__ RV, float* __restrict__ out) {
  int idx4 = blockIdx.x * 256 + threadIdx.x;
  int i4p = idx4 & 15;
  int n = (idx4 >> 4) & 1023;
  int b = idx4 >> 14;
  int pidx = n * 128 + b * 16 + i4p;
  float4 a0 = reinterpret_cast<const float4*>(P0)[pidx];
  float4 a1 = reinterpret_cast<const float4*>(P1)[pidx];
  float4 a2 = reinterpret_cast<const float4*>(P2)[pidx];
  float4 a3 = reinterpret_cast<const float4*>(P3)[pidx];
  float4 d = reinterpret_cast<const float4*>(RV + (size_t)b * 64)[i4p];
  float wv = w1[n];
  float4 r;
  r.x = CFINAL * (a0.x + a1.x + a2.x + a3.x + wv * d.x);
  r.y = CFINAL * (a0.y + a1.y + a2.y + a3.y + wv * d.y);
  r.z = CFINAL * (a0.z + a1.z + a2.z + a3.z + wv * d.z);
  r.w = CFINAL * (a0.w + a1.w + a2.w + a3.w + wv * d.w);
  reinterpret_cast<float4*>(out)[idx4] = r;
}

extern "C" void kernel_launch(void* const* d_in, const int* in_sizes, int n_in,
                              void* d_out, int out_size, void* d_ws, size_t ws_size,
                              hipStream_t stream) {
  (void)in_sizes; (void)n_in; (void)out_size;
  const float* xy  = (const float*)d_in[1];
  const float* kW1 = (const float*)d_in[3];
  const float* kb1 = (const float*)d_in[4];
  const float* kW2 = (const float*)d_in[5];
  const float* kb2 = (const float*)d_in[6];
  const float* kW3 = (const float*)d_in[7];
  const float* kb3 = (const float*)d_in[8];
  const float* fW1 = (const float*)d_in[9];
  const float* fb1 = (const float*)d_in[10];
  const float* fW2 = (const float*)d_in[11];
  const float* fb2 = (const float*)d_in[12];
  const float* fW3 = (const float*)d_in[13];
  const float* fb3 = (const float*)d_in[14];
  const float* Wq  = (const float*)d_in[15];
  const float* bq  = (const float*)d_in[16];
  const float* Wk  = (const float*)d_in[17];
  const float* bk  = (const float*)d_in[18];
  const float* lng = (const float*)d_in[19];
  const float* lnb = (const float*)d_in[20];
  float* ws = (float*)d_ws;
  float* out = (float*)d_out;
  if (ws_size < WS_FLOATS * sizeof(float)) return;  // visible failure, no OOB

  float* V   = ws + OFF_V;
  float* U1K = ws + OFF_U1K;
  float* U2K = ws + OFF_U2K;
  float* U1F = ws + OFF_U1F;
  float* U2F = ws + OFF_U2F;
  float* GPb = ws + OFF_GP;
  float* SPb = ws + OFF_SP;
  float* LNP = ws + OFF_LNP;
  float* W1v = ws + OFF_W1;
  // overlays
  float* G    = ws + OFF_U1K;
  float* SV   = ws + OFF_U1F;
  float* A    = ws + OFF_A;
  float* RV   = ws + OFF_RV;
  float* STAT = ws + OFF_LNP;               // reuses LNP after k_apply0
  ushort* Wbf  = (ushort*)(ws + OFF_W);
  ushort* WTW  = (ushort*)(ws + OFF_W + 524288);
  ushort* Wfbf = (ushort*)(ws + OFF_WF);
  ushort* WTF  = (ushort*)(ws + OFF_WF + 524288);
  ushort* ZT   = (ushort*)(ws + OFF_MID);
  float* Ep   = ws + OFF_ZU;
  float* Fp   = ws + OFF_ZU + 49152;
  float* Gpp  = ws + OFF_ZU + 49920;
  float* Cp   = ws + OFF_ZU + 50688;
  float* P0   = ws + OFF_GP;
  float* P1   = ws + OFF_GP + 524288;
  float* P2   = ws + OFF_MID + 524288;
  float* P3   = ws + OFF_ZU;

  k_pre_u<<<dim3(4), dim3(256), 0, stream>>>(kW1, kb1, fW1, fb1, U1K, U2K, U1F, U2F);
  k_mlp2<<<dim3(1024, 2), dim3(256), 0, stream>>>(U1K, U2K, kW2, kb2, kW3, kb3,
                                                  U1F, U2F, fW2, fb2, fW3, fb3, Wbf, Wfbf);
  k_cvtTb<<<dim3(16, 16, 2), dim3(256), 0, stream>>>(Wbf, Wfbf, WTW, WTF);
  k_colsumT<<<dim3(64), dim3(256), 0, stream>>>(WTW, WTF, W1v);
  k_eprep<<<dim3(RH, 3), dim3(256), 0, stream>>>(Wq, bq, Wk, bk, Ep, Fp, Gpp, Cp);

  k_redsum<<<dim3(32, 8), dim3(256), 0, stream>>>(xy, LNP);
  k_apply0<<<dim3(32, 8), dim3(256), 0, stream>>>(xy, lng, lnb, LNP, V, GPb, SPb);

  for (int j = 0; j < 2; j++) {
    k_gred<<<dim3(16, 8), dim3(256), 0, stream>>>(GPb, SPb, G, SV, 32);
    k_headsA2<<<dim3(8), dim3(256), 0, stream>>>(G, SV, Ep, Fp, Gpp, Cp, j, DXDYf * SCALEf, 1,
                                                 A, RV, STAT);
    k_midapply<<<dim3(32, 8), dim3(256), 0, stream>>>(
        V, A, RV, STAT, lng + (size_t)(j + 1) * 131072, lnb + (size_t)(j + 1) * 131072,
        (j == 1) ? xy : nullptr, GPb, SPb, (j == 1) ? 16 : 32);
  }
  k_gred<<<dim3(16, 8), dim3(256), 0, stream>>>(GPb, SPb, G, SV, 16);
  k_headsA2<<<dim3(8), dim3(256), 0, stream>>>(G, SV, Ep, Fp, Gpp, Cp, 2, 1.0f, 0, A, RV, STAT);
  k_y<<<dim3(32, 8, 2), dim3(256), 0, stream>>>(V, A, ZT);
  k_final_mfma<<<dim3(32, 8, 4), dim3(256), 0, stream>>>(WTW, WTF, ZT, P0, P1, P2, P3);
  k_final_red<<<dim3(512), dim3(256), 0, stream>>>(P0, P1, P2, P3, W1v, RV, out);
}